// Round 4
// baseline (198.234 us; speedup 1.0000x reference)
//
#include <hip/hip_runtime.h>
#include <hip/hip_bf16.h>
#include <math.h>

typedef __bf16 bf16x8 __attribute__((ext_vector_type(8)));
typedef float  f32x4  __attribute__((ext_vector_type(4)));
typedef float  f32x4v __attribute__((ext_vector_type(4)));
typedef unsigned short ushort_t;
typedef ushort_t u16x4 __attribute__((ext_vector_type(4)));
typedef ushort_t u16x8 __attribute__((ext_vector_type(8)));

__device__ __forceinline__ ushort_t f2bf(float f) {
    unsigned u = __builtin_bit_cast(unsigned, f);
    u += 0x7FFFu + ((u >> 16) & 1u);
    return (ushort_t)(u >> 16);
}
__device__ __forceinline__ float bf2f(ushort_t b) {
    return __builtin_bit_cast(float, (unsigned)b << 16);
}

// XCD-aware bijective remap (m157/m204). Requires total grid % 8 == 0.
__device__ __forceinline__ void xcd_remap(int& bx, int& by, int& bz) {
    const int gx = gridDim.x, gy = gridDim.y;
    const int nwg = gx * gy * gridDim.z;
    const int lin = (blockIdx.z * gy + blockIdx.y) * gx + blockIdx.x;
    const int chunk = nwg >> 3;
    int nid = (lin & 7) * chunk + (lin >> 3);
    bx = nid % gx; nid /= gx;
    by = nid % gy; bz = nid / gy;
}

// ---------------- fp32 -> bf16 conversion (z-batched, up to 4 arrays) --------
__global__ __launch_bounds__(256) void cvt_multi(const float* __restrict__ i0, const float* __restrict__ i1,
                                                 const float* __restrict__ i2, const float* __restrict__ i3,
                                                 ushort_t* __restrict__ o0, ushort_t* __restrict__ o1,
                                                 ushort_t* __restrict__ o2, ushort_t* __restrict__ o3, int n4) {
    const int z = blockIdx.z;
    const float* in  = z == 0 ? i0 : z == 1 ? i1 : z == 2 ? i2 : i3;
    ushort_t*    out = z == 0 ? o0 : z == 1 ? o1 : z == 2 ? o2 : o3;
    int i = blockIdx.x * 256 + threadIdx.x;
    if (i >= n4) return;
    f32x4v v = ((const f32x4v*)in)[i];
    u16x4 o = { f2bf(v.x), f2bf(v.y), f2bf(v.z), f2bf(v.w) };
    ((u16x4*)out)[i] = o;
}

__global__ __launch_bounds__(256) void zero_f32(float* __restrict__ p, int n) {
    int i = blockIdx.x * 256 + threadIdx.x;
    if (i < n) p[i] = 0.f;
}

// ---------------- NT GEMM: C = A(MxK) * B(NxK)^T ----------------
#define M_SEXP 0   // P~ = exp(scale*acc) bf16 out, batched, + rowsum atomics
#define M_PVN  1   // bf16 out * (1/rowsum[row]), batched
#define M_OUT  2   // fp32 out + bias

#define BM 128
#define BN 128
#define BK 32

#define GEMM_CORE(Ab_, lda_, Bb_, ldb_, Kdim_)                                              \
    __shared__ __align__(16) ushort_t lds[2][2][BM * BK];                                   \
    const int tid  = threadIdx.x;                                                           \
    const int lane = tid & 63;                                                              \
    const int wave = tid >> 6;                                                              \
    const int wr = wave >> 1, wc = wave & 1;                                                \
    f32x4 acc[4][4];                                                                        \
    _Pragma("unroll") for (int i = 0; i < 4; ++i)                                           \
        _Pragma("unroll") for (int j = 0; j < 4; ++j)                                       \
            acc[i][j] = (f32x4){0.f, 0.f, 0.f, 0.f};                                        \
    auto stage = [&](int buf, int kt) {                                                     \
        const int k0 = kt * BK;                                                             \
        _Pragma("unroll") for (int rnd = 0; rnd < 2; ++rnd) {                               \
            const int c    = tid + rnd * 256;                                               \
            const int row  = c >> 2;                                                        \
            const int slot = (c & 3) ^ (row & 3);                                           \
            const ushort_t* ga = (Ab_) + (tM + row) * (long long)(lda_) + k0 + slot * 8;    \
            const ushort_t* gb = (Bb_) + (tN + row) * (long long)(ldb_) + k0 + slot * 8;    \
            ushort_t* la = &lds[buf][0][(rnd * 256 + wave * 64) * 8];                       \
            ushort_t* lb = &lds[buf][1][(rnd * 256 + wave * 64) * 8];                       \
            __builtin_amdgcn_global_load_lds((const __attribute__((address_space(1))) void*)ga, \
                                             (__attribute__((address_space(3))) void*)la, 16, 0, 0); \
            __builtin_amdgcn_global_load_lds((const __attribute__((address_space(1))) void*)gb, \
                                             (__attribute__((address_space(3))) void*)lb, 16, 0, 0); \
        }                                                                                   \
    };                                                                                      \
    auto compute = [&](int buf) {                                                           \
        const int kb  = lane >> 4;                                                          \
        const int r16 = lane & 15;                                                          \
        bf16x8 af[4], bfr[4];                                                               \
        _Pragma("unroll") for (int mi = 0; mi < 4; ++mi) {                                  \
            const int row = wr * 64 + mi * 16 + r16;                                        \
            const int off = row * 64 + ((kb ^ (row & 3)) << 4);                             \
            af[mi] = *(const bf16x8*)((const char*)lds[buf][0] + off);                      \
        }                                                                                   \
        _Pragma("unroll") for (int ni = 0; ni < 4; ++ni) {                                  \
            const int row = wc * 64 + ni * 16 + r16;                                        \
            const int off = row * 64 + ((kb ^ (row & 3)) << 4);                             \
            bfr[ni] = *(const bf16x8*)((const char*)lds[buf][1] + off);                     \
        }                                                                                   \
        _Pragma("unroll") for (int mi = 0; mi < 4; ++mi)                                    \
            _Pragma("unroll") for (int ni = 0; ni < 4; ++ni)                                \
                acc[mi][ni] = __builtin_amdgcn_mfma_f32_16x16x32_bf16(af[mi], bfr[ni], acc[mi][ni], 0, 0, 0); \
    };                                                                                      \
    const int NT = (Kdim_) / BK;                                                            \
    stage(0, 0);                                                                            \
    __syncthreads();                                                                        \
    int cur = 0;                                                                            \
    for (int kt = 0; kt + 1 < NT; ++kt) {                                                   \
        stage(cur ^ 1, kt + 1);                                                             \
        compute(cur);                                                                       \
        __syncthreads();                                                                    \
        cur ^= 1;                                                                           \
    }                                                                                       \
    compute(cur);                                                                           \
    const int rquad = (lane >> 4) * 4;                                                      \
    const int cl    = lane & 15;

template<int MODE>
__global__ __launch_bounds__(256, 5)   // 5 blocks/CU (LDS-capped); was 3 — proj was latency-bound at 28% occupancy
void gemm_nt(const ushort_t* __restrict__ A, int lda, long long aBatch,
             const ushort_t* __restrict__ B, int ldb, long long bBatch,
             void* __restrict__ Cv, int ldc, long long cBatch,
             const float* __restrict__ bias, float* __restrict__ rowsum,
             float scale, int K)
{
    int bx, by, bz;
    xcd_remap(bx, by, bz);
    const long long tM = (long long)by * BM;
    const long long tN = (long long)bx * BN;
    const int z = bz;
    const ushort_t* Ab = A + (long long)z * aBatch;
    const ushort_t* Bb = B + (long long)z * bBatch;

    GEMM_CORE(Ab, lda, Bb, ldb, K)

#pragma unroll
    for (int mi = 0; mi < 4; ++mi) {
        const long long r = tM + wr * 64 + mi * 16 + rquad;   // rows r..r+3
        if constexpr (MODE == M_SEXP) {
            ushort_t* out = (ushort_t*)Cv + (long long)z * cBatch;
            float rs[4] = {0.f, 0.f, 0.f, 0.f};
#pragma unroll
            for (int ni = 0; ni < 4; ++ni) {
                f32x4 v = acc[mi][ni];
                const long long c = tN + wc * 64 + ni * 16 + cl;
#pragma unroll
                for (int j = 0; j < 4; ++j) {
                    float p = __expf(v[j] * scale);
                    ushort_t pb = f2bf(p);
                    out[(r + j) * ldc + c] = pb;
                    rs[j] += bf2f(pb);     // sum exactly what PV will read
                }
            }
#pragma unroll
            for (int j = 0; j < 4; ++j) {
                float s = rs[j];
                s += __shfl_xor(s, 1, 64);
                s += __shfl_xor(s, 2, 64);
                s += __shfl_xor(s, 4, 64);
                s += __shfl_xor(s, 8, 64);
                if (cl == 0) atomicAdd(&rowsum[(long long)z * 2048 + r + j], s);
            }
        } else if constexpr (MODE == M_PVN) {
            ushort_t* out = (ushort_t*)Cv + (long long)z * cBatch;
            float inv[4];
#pragma unroll
            for (int j = 0; j < 4; ++j)
                inv[j] = 1.0f / rowsum[(long long)z * 2048 + r + j];
#pragma unroll
            for (int ni = 0; ni < 4; ++ni) {
                f32x4 v = acc[mi][ni];
                const long long c = tN + wc * 64 + ni * 16 + cl;
#pragma unroll
                for (int j = 0; j < 4; ++j)
                    out[(r + j) * ldc + c] = f2bf(v[j] * inv[j]);
            }
        } else {  // M_OUT
            float* out = (float*)Cv;
#pragma unroll
            for (int ni = 0; ni < 4; ++ni) {
                f32x4 v = acc[mi][ni];
                const long long c = tN + wc * 64 + ni * 16 + cl;
                const float bc = bias[c];
#pragma unroll
                for (int j = 0; j < 4; ++j)
                    out[(r + j) * ldc + c] = v[j] + bc;
            }
        }
    }
}

// ------------- batched QKV projection --------------------------------------
// z=0: qp = qb@Wq^T+bq   [8192x768]
// z=1: kp = kb@Wk^T+bk   [8192x768]
// z=2: vpT = Wv@vb^T + bv (per-ROW bias) -> [768][8192] (Vp^T, col = global token)
__global__ __launch_bounds__(256, 5)
void proj_qkv(const ushort_t* __restrict__ a0, const ushort_t* __restrict__ a1, const ushort_t* __restrict__ a2,
              const ushort_t* __restrict__ w0, const ushort_t* __restrict__ w1, const ushort_t* __restrict__ w2,
              const float* __restrict__ b0, const float* __restrict__ b1, const float* __restrict__ b2,
              ushort_t* __restrict__ dq, ushort_t* __restrict__ dk, ushort_t* __restrict__ dvT)
{
    int bx, by, bz;
    xcd_remap(bx, by, bz);
    const int z = bz;
    const long long tM = (z < 2) ? (long long)by * BM : (long long)bx * BM;
    const long long tN = (z < 2) ? (long long)bx * BN : (long long)by * BN;
    const ushort_t* Ab = z == 0 ? a0 : z == 1 ? a1 : w2;
    const ushort_t* Bb = z == 0 ? w0 : z == 1 ? w1 : a2;
    const float* bias  = z == 0 ? b0 : z == 1 ? b1 : b2;

    GEMM_CORE(Ab, 768, Bb, 768, 768)

#pragma unroll
    for (int mi = 0; mi < 4; ++mi) {
        const long long r = tM + wr * 64 + mi * 16 + rquad;
        if (z < 2) {
            ushort_t* dst = z == 0 ? dq : dk;
#pragma unroll
            for (int ni = 0; ni < 4; ++ni) {
                f32x4 v = acc[mi][ni];
                const long long c = tN + wc * 64 + ni * 16 + cl;
                const float bc = bias[c];
#pragma unroll
                for (int j = 0; j < 4; ++j)
                    dst[(r + j) * 768 + c] = f2bf(v[j] + bc);
            }
        } else {
#pragma unroll
            for (int ni = 0; ni < 4; ++ni) {
                f32x4 v = acc[mi][ni];
                const long long c = tN + wc * 64 + ni * 16 + cl;
#pragma unroll
                for (int j = 0; j < 4; ++j)
                    dvT[(r + j) * 8192 + c] = f2bf(v[j] + bias[r + j]);
            }
        }
    }
}

// ---------------- launch ----------------
extern "C" void kernel_launch(void* const* d_in, const int* in_sizes, int n_in,
                              void* d_out, int out_size, void* d_ws, size_t ws_size,
                              hipStream_t stream) {
    (void)in_sizes; (void)n_in; (void)out_size; (void)ws_size;
    const float* q  = (const float*)d_in[0];
    const float* k  = (const float*)d_in[1];
    const float* v  = (const float*)d_in[2];
    const float* Wq = (const float*)d_in[3];
    const float* bq = (const float*)d_in[4];
    const float* Wk = (const float*)d_in[5];
    const float* bk = (const float*)d_in[6];
    const float* Wv = (const float*)d_in[7];
    const float* bv = (const float*)d_in[8];
    const float* Wp = (const float*)d_in[9];
    const float* bp = (const float*)d_in[10];
    float* out = (float*)d_out;

    char* ws = (char*)d_ws;
    ushort_t* qb  = (ushort_t*)(ws);
    ushort_t* kb  = (ushort_t*)(ws + 12582912LL);
    ushort_t* vb  = (ushort_t*)(ws + 25165824LL);
    ushort_t* P   = (ushort_t*)(ws);
    float* rowsum = (float*)(ws + 33554432LL);
    ushort_t* Wqb = (ushort_t*)(ws + 67108864LL);
    ushort_t* Wkb = (ushort_t*)(ws + 68288512LL);
    ushort_t* Wvb = (ushort_t*)(ws + 69468160LL);
    ushort_t* Wpb = (ushort_t*)(ws + 70647808LL);
    ushort_t* qp  = (ushort_t*)(ws + 71827456LL);    // [8192][768] bf16
    ushort_t* kp  = (ushort_t*)(ws + 84410368LL);    // [8192][768] bf16
    ushort_t* vpT = (ushort_t*)(ws + 96993280LL);    // [768][8192] bf16
    ushort_t* Ob  = qp;                              // O overlays dead qp

    const float scale = 1.0f / sqrtf(768.0f);

    cvt_multi<<<dim3(6144, 1, 3), 256, 0, stream>>>(q, k, v, nullptr, qb, kb, vb, nullptr, 1572864);
    cvt_multi<<<dim3(576, 1, 4), 256, 0, stream>>>(Wq, Wk, Wv, Wp, Wqb, Wkb, Wvb, Wpb, 147456);

    proj_qkv<<<dim3(6, 64, 3), 256, 0, stream>>>(qb, kb, vb, Wqb, Wkb, Wvb, bq, bk, bv, qp, kp, vpT);

    zero_f32<<<32, 256, 0, stream>>>(rowsum, 8192);

    gemm_nt<M_SEXP><<<dim3(16, 16, 4), 256, 0, stream>>>(qp, 768, 1572864, kp, 768, 1572864,
                                                         P, 2048, 4194304, nullptr, rowsum, scale, 768);

    gemm_nt<M_PVN><<<dim3(6, 16, 4), 256, 0, stream>>>(P, 2048, 4194304, vpT, 8192, 2048,
                                                       Ob, 768, 1572864, nullptr, rowsum, 1.0f, 2048);

    gemm_nt<M_OUT><<<dim3(6, 64, 1), 256, 0, stream>>>(Ob, 768, 0, Wpb, 768, 0, out, 768, 0, bp, nullptr, 1.0f, 768);
}

// Round 5
// 169.416 us; speedup vs baseline: 1.1701x; 1.1701x over previous
//
#include <hip/hip_runtime.h>
#include <hip/hip_bf16.h>
#include <math.h>

typedef __bf16 bf16x8 __attribute__((ext_vector_type(8)));
typedef float  f32x4  __attribute__((ext_vector_type(4)));
typedef float  f32x4v __attribute__((ext_vector_type(4)));
typedef unsigned short ushort_t;
typedef ushort_t u16x4 __attribute__((ext_vector_type(4)));
typedef ushort_t u16x8 __attribute__((ext_vector_type(8)));

__device__ __forceinline__ ushort_t f2bf(float f) {
    unsigned u = __builtin_bit_cast(unsigned, f);
    u += 0x7FFFu + ((u >> 16) & 1u);
    return (ushort_t)(u >> 16);
}
__device__ __forceinline__ float bf2f(ushort_t b) {
    return __builtin_bit_cast(float, (unsigned)b << 16);
}

// XCD-aware bijective remap (m157/m204). Requires total grid % 8 == 0.
__device__ __forceinline__ void xcd_remap(int& bx, int& by, int& bz) {
    const int gx = gridDim.x, gy = gridDim.y;
    const int nwg = gx * gy * gridDim.z;
    const int lin = (blockIdx.z * gy + blockIdx.y) * gx + blockIdx.x;
    const int chunk = nwg >> 3;
    int nid = (lin & 7) * chunk + (lin >> 3);
    bx = nid % gx; nid /= gx;
    by = nid % gy; bz = nid / gy;
}

// ---------------- fp32 -> bf16 conversion (z-batched, up to 4 arrays) --------
__global__ __launch_bounds__(256) void cvt_multi(const float* __restrict__ i0, const float* __restrict__ i1,
                                                 const float* __restrict__ i2, const float* __restrict__ i3,
                                                 ushort_t* __restrict__ o0, ushort_t* __restrict__ o1,
                                                 ushort_t* __restrict__ o2, ushort_t* __restrict__ o3, int n4) {
    const int z = blockIdx.z;
    const float* in  = z == 0 ? i0 : z == 1 ? i1 : z == 2 ? i2 : i3;
    ushort_t*    out = z == 0 ? o0 : z == 1 ? o1 : z == 2 ? o2 : o3;
    int i = blockIdx.x * 256 + threadIdx.x;
    if (i >= n4) return;
    f32x4v v = ((const f32x4v*)in)[i];
    u16x4 o = { f2bf(v.x), f2bf(v.y), f2bf(v.z), f2bf(v.w) };
    ((u16x4*)out)[i] = o;
}

__global__ __launch_bounds__(256) void zero_f32(float* __restrict__ p, int n) {
    int i = blockIdx.x * 256 + threadIdx.x;
    if (i < n) p[i] = 0.f;
}

// ---------------- NT GEMM: C = A(MxK) * B(NxK)^T ----------------
#define M_SEXP 0   // P~ = exp(scale*acc) bf16 out, batched, + rowsum atomics
#define M_PVN  1   // bf16 out * (1/rowsum[row]), batched
#define M_OUT  2   // fp32 out + bias

#define BM 128
#define BN 128
#define BK 32

// 3-buffer, 2-ahead prefetch pipeline with COUNTED vmcnt (T3/T4, m201 template).
// Never drains vmcnt to 0 in the main loop; sched_barrier(0) pins compute
// before the closing barrier (rule #18); 3 buffers make the re-staged buffer
// 3 tiles stale so the async LDS-write can't race in-flight ds_reads.
#define GEMM_CORE(Ab_, lda_, Bb_, ldb_, Kdim_)                                              \
    __shared__ __align__(16) ushort_t lds[3][2][BM * BK];                                   \
    const int tid  = threadIdx.x;                                                           \
    const int lane = tid & 63;                                                              \
    const int wave = tid >> 6;                                                              \
    const int wr = wave >> 1, wc = wave & 1;                                                \
    f32x4 acc[4][4];                                                                        \
    _Pragma("unroll") for (int i = 0; i < 4; ++i)                                           \
        _Pragma("unroll") for (int j = 0; j < 4; ++j)                                       \
            acc[i][j] = (f32x4){0.f, 0.f, 0.f, 0.f};                                        \
    auto stage = [&](int kt) {                                                              \
        const int buf = kt % 3;                                                             \
        const int k0 = kt * BK;                                                             \
        _Pragma("unroll") for (int rnd = 0; rnd < 2; ++rnd) {                               \
            const int c    = tid + rnd * 256;                                               \
            const int row  = c >> 2;                                                        \
            const int slot = (c & 3) ^ (row & 3);                                           \
            const ushort_t* ga = (Ab_) + (tM + row) * (long long)(lda_) + k0 + slot * 8;    \
            const ushort_t* gb = (Bb_) + (tN + row) * (long long)(ldb_) + k0 + slot * 8;    \
            ushort_t* la = &lds[buf][0][(rnd * 256 + wave * 64) * 8];                       \
            ushort_t* lb = &lds[buf][1][(rnd * 256 + wave * 64) * 8];                       \
            __builtin_amdgcn_global_load_lds((const __attribute__((address_space(1))) void*)ga, \
                                             (__attribute__((address_space(3))) void*)la, 16, 0, 0); \
            __builtin_amdgcn_global_load_lds((const __attribute__((address_space(1))) void*)gb, \
                                             (__attribute__((address_space(3))) void*)lb, 16, 0, 0); \
        }                                                                                   \
    };                                                                                      \
    auto compute = [&](int kt) {                                                            \
        const int buf = kt % 3;                                                             \
        const int kb  = lane >> 4;                                                          \
        const int r16 = lane & 15;                                                          \
        bf16x8 af[4], bfr[4];                                                               \
        _Pragma("unroll") for (int mi = 0; mi < 4; ++mi) {                                  \
            const int row = wr * 64 + mi * 16 + r16;                                        \
            const int off = row * 64 + ((kb ^ (row & 3)) << 4);                             \
            af[mi] = *(const bf16x8*)((const char*)lds[buf][0] + off);                      \
        }                                                                                   \
        _Pragma("unroll") for (int ni = 0; ni < 4; ++ni) {                                  \
            const int row = wc * 64 + ni * 16 + r16;                                        \
            const int off = row * 64 + ((kb ^ (row & 3)) << 4);                             \
            bfr[ni] = *(const bf16x8*)((const char*)lds[buf][1] + off);                     \
        }                                                                                   \
        _Pragma("unroll") for (int mi = 0; mi < 4; ++mi)                                    \
            _Pragma("unroll") for (int ni = 0; ni < 4; ++ni)                                \
                acc[mi][ni] = __builtin_amdgcn_mfma_f32_16x16x32_bf16(af[mi], bfr[ni], acc[mi][ni], 0, 0, 0); \
    };                                                                                      \
    const int NT = (Kdim_) / BK;                                                            \
    stage(0);                                                                               \
    stage(1);                                                                               \
    for (int t = 0; t < NT; ++t) {                                                          \
        if (t + 2 < NT) stage(t + 2);                                                       \
        const int rem = NT - 1 - t;                                                         \
        if (rem >= 2)      asm volatile("s_waitcnt vmcnt(8)" ::: "memory");                 \
        else if (rem == 1) asm volatile("s_waitcnt vmcnt(4)" ::: "memory");                 \
        else               asm volatile("s_waitcnt vmcnt(0)" ::: "memory");                 \
        __builtin_amdgcn_s_barrier();                                                       \
        compute(t);                                                                         \
        asm volatile("s_waitcnt lgkmcnt(0)" ::: "memory");                                  \
        __builtin_amdgcn_sched_barrier(0);                                                  \
        __builtin_amdgcn_s_barrier();                                                       \
    }                                                                                       \
    const int rquad = (lane >> 4) * 4;                                                      \
    const int cl    = lane & 15;

template<int MODE>
__global__ __launch_bounds__(256, 3)   // 3 blocks/CU: 48KB LDS/block; regs ~124 (60 VGPR + 64 AGPR unified) need >=170/wave budget
void gemm_nt(const ushort_t* __restrict__ A, int lda, long long aBatch,
             const ushort_t* __restrict__ B, int ldb, long long bBatch,
             void* __restrict__ Cv, int ldc, long long cBatch,
             const float* __restrict__ bias, float* __restrict__ rowsum,
             float scale, int K)
{
    int bx, by, bz;
    xcd_remap(bx, by, bz);
    const long long tM = (long long)by * BM;
    const long long tN = (long long)bx * BN;
    const int z = bz;
    const ushort_t* Ab = A + (long long)z * aBatch;
    const ushort_t* Bb = B + (long long)z * bBatch;

    GEMM_CORE(Ab, lda, Bb, ldb, K)

#pragma unroll
    for (int mi = 0; mi < 4; ++mi) {
        const long long r = tM + wr * 64 + mi * 16 + rquad;   // rows r..r+3
        if constexpr (MODE == M_SEXP) {
            ushort_t* out = (ushort_t*)Cv + (long long)z * cBatch;
            float rs[4] = {0.f, 0.f, 0.f, 0.f};
#pragma unroll
            for (int ni = 0; ni < 4; ++ni) {
                f32x4 v = acc[mi][ni];
                const long long c = tN + wc * 64 + ni * 16 + cl;
#pragma unroll
                for (int j = 0; j < 4; ++j) {
                    float p = __expf(v[j] * scale);
                    ushort_t pb = f2bf(p);
                    out[(r + j) * ldc + c] = pb;
                    rs[j] += bf2f(pb);     // sum exactly what PV will read
                }
            }
#pragma unroll
            for (int j = 0; j < 4; ++j) {
                float s = rs[j];
                s += __shfl_xor(s, 1, 64);
                s += __shfl_xor(s, 2, 64);
                s += __shfl_xor(s, 4, 64);
                s += __shfl_xor(s, 8, 64);
                if (cl == 0) atomicAdd(&rowsum[(long long)z * 2048 + r + j], s);
            }
        } else if constexpr (MODE == M_PVN) {
            ushort_t* out = (ushort_t*)Cv + (long long)z * cBatch;
            float inv[4];
#pragma unroll
            for (int j = 0; j < 4; ++j)
                inv[j] = 1.0f / rowsum[(long long)z * 2048 + r + j];
#pragma unroll
            for (int ni = 0; ni < 4; ++ni) {
                f32x4 v = acc[mi][ni];
                const long long c = tN + wc * 64 + ni * 16 + cl;
#pragma unroll
                for (int j = 0; j < 4; ++j)
                    out[(r + j) * ldc + c] = f2bf(v[j] * inv[j]);
            }
        } else {  // M_OUT
            float* out = (float*)Cv;
#pragma unroll
            for (int ni = 0; ni < 4; ++ni) {
                f32x4 v = acc[mi][ni];
                const long long c = tN + wc * 64 + ni * 16 + cl;
                const float bc = bias[c];
#pragma unroll
                for (int j = 0; j < 4; ++j)
                    out[(r + j) * ldc + c] = v[j] + bc;
            }
        }
    }
}

// ------------- batched QKV projection --------------------------------------
// z=0: qp = qb@Wq^T+bq   [8192x768]
// z=1: kp = kb@Wk^T+bk   [8192x768]
// z=2: vpT = Wv@vb^T + bv (per-ROW bias) -> [768][8192] (Vp^T, col = global token)
__global__ __launch_bounds__(256, 3)
void proj_qkv(const ushort_t* __restrict__ a0, const ushort_t* __restrict__ a1, const ushort_t* __restrict__ a2,
              const ushort_t* __restrict__ w0, const ushort_t* __restrict__ w1, const ushort_t* __restrict__ w2,
              const float* __restrict__ b0, const float* __restrict__ b1, const float* __restrict__ b2,
              ushort_t* __restrict__ dq, ushort_t* __restrict__ dk, ushort_t* __restrict__ dvT)
{
    int bx, by, bz;
    xcd_remap(bx, by, bz);
    const int z = bz;
    const long long tM = (z < 2) ? (long long)by * BM : (long long)bx * BM;
    const long long tN = (z < 2) ? (long long)bx * BN : (long long)by * BN;
    const ushort_t* Ab = z == 0 ? a0 : z == 1 ? a1 : w2;
    const ushort_t* Bb = z == 0 ? w0 : z == 1 ? w1 : a2;
    const float* bias  = z == 0 ? b0 : z == 1 ? b1 : b2;

    GEMM_CORE(Ab, 768, Bb, 768, 768)

#pragma unroll
    for (int mi = 0; mi < 4; ++mi) {
        const long long r = tM + wr * 64 + mi * 16 + rquad;
        if (z < 2) {
            ushort_t* dst = z == 0 ? dq : dk;
#pragma unroll
            for (int ni = 0; ni < 4; ++ni) {
                f32x4 v = acc[mi][ni];
                const long long c = tN + wc * 64 + ni * 16 + cl;
                const float bc = bias[c];
#pragma unroll
                for (int j = 0; j < 4; ++j)
                    dst[(r + j) * 768 + c] = f2bf(v[j] + bc);
            }
        } else {
#pragma unroll
            for (int ni = 0; ni < 4; ++ni) {
                f32x4 v = acc[mi][ni];
                const long long c = tN + wc * 64 + ni * 16 + cl;
#pragma unroll
                for (int j = 0; j < 4; ++j)
                    dvT[(r + j) * 8192 + c] = f2bf(v[j] + bias[r + j]);
            }
        }
    }
}

// ---------------- launch ----------------
extern "C" void kernel_launch(void* const* d_in, const int* in_sizes, int n_in,
                              void* d_out, int out_size, void* d_ws, size_t ws_size,
                              hipStream_t stream) {
    (void)in_sizes; (void)n_in; (void)out_size; (void)ws_size;
    const float* q  = (const float*)d_in[0];
    const float* k  = (const float*)d_in[1];
    const float* v  = (const float*)d_in[2];
    const float* Wq = (const float*)d_in[3];
    const float* bq = (const float*)d_in[4];
    const float* Wk = (const float*)d_in[5];
    const float* bk = (const float*)d_in[6];
    const float* Wv = (const float*)d_in[7];
    const float* bv = (const float*)d_in[8];
    const float* Wp = (const float*)d_in[9];
    const float* bp = (const float*)d_in[10];
    float* out = (float*)d_out;

    char* ws = (char*)d_ws;
    ushort_t* qb  = (ushort_t*)(ws);
    ushort_t* kb  = (ushort_t*)(ws + 12582912LL);
    ushort_t* vb  = (ushort_t*)(ws + 25165824LL);
    ushort_t* P   = (ushort_t*)(ws);
    float* rowsum = (float*)(ws + 33554432LL);
    ushort_t* Wqb = (ushort_t*)(ws + 67108864LL);
    ushort_t* Wkb = (ushort_t*)(ws + 68288512LL);
    ushort_t* Wvb = (ushort_t*)(ws + 69468160LL);
    ushort_t* Wpb = (ushort_t*)(ws + 70647808LL);
    ushort_t* qp  = (ushort_t*)(ws + 71827456LL);    // [8192][768] bf16
    ushort_t* kp  = (ushort_t*)(ws + 84410368LL);    // [8192][768] bf16
    ushort_t* vpT = (ushort_t*)(ws + 96993280LL);    // [768][8192] bf16
    ushort_t* Ob  = qp;                              // O overlays dead qp

    const float scale = 1.0f / sqrtf(768.0f);

    cvt_multi<<<dim3(6144, 1, 3), 256, 0, stream>>>(q, k, v, nullptr, qb, kb, vb, nullptr, 1572864);
    cvt_multi<<<dim3(576, 1, 4), 256, 0, stream>>>(Wq, Wk, Wv, Wp, Wqb, Wkb, Wvb, Wpb, 147456);

    proj_qkv<<<dim3(6, 64, 3), 256, 0, stream>>>(qb, kb, vb, Wqb, Wkb, Wvb, bq, bk, bv, qp, kp, vpT);

    zero_f32<<<32, 256, 0, stream>>>(rowsum, 8192);

    gemm_nt<M_SEXP><<<dim3(16, 16, 4), 256, 0, stream>>>(qp, 768, 1572864, kp, 768, 1572864,
                                                         P, 2048, 4194304, nullptr, rowsum, scale, 768);

    gemm_nt<M_PVN><<<dim3(6, 16, 4), 256, 0, stream>>>(P, 2048, 4194304, vpT, 8192, 2048,
                                                       Ob, 768, 1572864, nullptr, rowsum, 1.0f, 2048);

    gemm_nt<M_OUT><<<dim3(6, 64, 1), 256, 0, stream>>>(Ob, 768, 0, Wpb, 768, 0, out, 768, 0, bp, nullptr, 1.0f, 768);
}

// Round 6
// 169.245 us; speedup vs baseline: 1.1713x; 1.0010x over previous
//
#include <hip/hip_runtime.h>
#include <hip/hip_bf16.h>
#include <math.h>

typedef __bf16 bf16x8 __attribute__((ext_vector_type(8)));
typedef float  f32x4  __attribute__((ext_vector_type(4)));
typedef float  f32x4v __attribute__((ext_vector_type(4)));
typedef unsigned short ushort_t;
typedef ushort_t u16x4 __attribute__((ext_vector_type(4)));
typedef ushort_t u16x8 __attribute__((ext_vector_type(8)));

__device__ __forceinline__ ushort_t f2bf(float f) {
    unsigned u = __builtin_bit_cast(unsigned, f);
    u += 0x7FFFu + ((u >> 16) & 1u);
    return (ushort_t)(u >> 16);
}
__device__ __forceinline__ float bf2f(ushort_t b) {
    return __builtin_bit_cast(float, (unsigned)b << 16);
}

// XCD-aware bijective remap (m157/m204). Requires total grid % 8 == 0.
__device__ __forceinline__ void xcd_remap(int& bx, int& by, int& bz) {
    const int gx = gridDim.x, gy = gridDim.y;
    const int nwg = gx * gy * gridDim.z;
    const int lin = (blockIdx.z * gy + blockIdx.y) * gx + blockIdx.x;
    const int chunk = nwg >> 3;
    int nid = (lin & 7) * chunk + (lin >> 3);
    bx = nid % gx; nid /= gx;
    by = nid % gy; bz = nid / gy;
}

// ---------------- fp32 -> bf16 conversion (z-batched) ----------------
__global__ __launch_bounds__(256) void cvt_multi(const float* __restrict__ i0, const float* __restrict__ i1,
                                                 const float* __restrict__ i2, const float* __restrict__ i3,
                                                 ushort_t* __restrict__ o0, ushort_t* __restrict__ o1,
                                                 ushort_t* __restrict__ o2, ushort_t* __restrict__ o3, int n4) {
    const int z = blockIdx.z;
    const float* in  = z == 0 ? i0 : z == 1 ? i1 : z == 2 ? i2 : i3;
    ushort_t*    out = z == 0 ? o0 : z == 1 ? o1 : z == 2 ? o2 : o3;
    int i = blockIdx.x * 256 + threadIdx.x;
    if (i >= n4) return;
    f32x4v v = ((const f32x4v*)in)[i];
    u16x4 o = { f2bf(v.x), f2bf(v.y), f2bf(v.z), f2bf(v.w) };
    ((u16x4*)out)[i] = o;
}

__global__ __launch_bounds__(256) void zero_f32(float* __restrict__ p, int n) {
    int i = blockIdx.x * 256 + threadIdx.x;
    if (i < n) p[i] = 0.f;
}

// ============================================================================
// 256x256 / BK=64 / 8-wave core (m230-style 256^2 structure, T2-full swizzle,
// T5 setprio). Stage-next -> compute(64 MFMA/wave) -> __syncthreads per K-tile.
// LDS 128KB: [dbuf][A,B][half(128 rows)][128*64 bf16], 16B-granular swizzle
// slot^(row&7) applied inverse-on-source (linear gload_lds dest, rule #21).
// ============================================================================
#define GEMM256_CORE(Ab_, lda_, Bb_, ldb_, Kdim_)                                           \
    __shared__ __align__(16) ushort_t lds[2][2][2][128 * 64];                               \
    const int tid  = threadIdx.x;                                                           \
    const int lane = tid & 63;                                                              \
    const int wave = tid >> 6;                                                              \
    const int wm = wave >> 2, wn = wave & 3;                                                \
    const int r16 = lane & 15, kb = lane >> 4;                                              \
    f32x4 acc[8][4];                                                                        \
    _Pragma("unroll") for (int i = 0; i < 8; ++i)                                           \
        _Pragma("unroll") for (int j = 0; j < 4; ++j)                                       \
            acc[i][j] = (f32x4){0.f, 0.f, 0.f, 0.f};                                        \
    auto stage = [&](int kt) {                                                              \
        const int d  = kt & 1;                                                              \
        const int k0 = kt * 64;                                                             \
        _Pragma("unroll") for (int arr = 0; arr < 2; ++arr)                                 \
        _Pragma("unroll") for (int h = 0; h < 2; ++h)                                       \
        _Pragma("unroll") for (int l = 0; l < 2; ++l) {                                     \
            const int idx = l * 512 + tid;                                                  \
            const int row = idx >> 3, sl = idx & 7;                                         \
            const int ssrc = sl ^ (row & 7);                                                \
            const long long grow = h * 128 + row;                                           \
            const ushort_t* g = (arr == 0)                                                  \
                ? (Ab_) + (tM + grow) * (long long)(lda_) + k0 + ssrc * 8                   \
                : (Bb_) + (tN + grow) * (long long)(ldb_) + k0 + ssrc * 8;                  \
            ushort_t* lp = &lds[d][arr][h][idx * 8];                                        \
            __builtin_amdgcn_global_load_lds((const __attribute__((address_space(1))) void*)g, \
                                             (__attribute__((address_space(3))) void*)lp, 16, 0, 0); \
        }                                                                                   \
    };                                                                                      \
    auto compute = [&](int kt) {                                                            \
        const int d = kt & 1;                                                               \
        _Pragma("unroll") for (int kk = 0; kk < 2; ++kk) {                                  \
            bf16x8 bfr[4];                                                                  \
            _Pragma("unroll") for (int ni = 0; ni < 4; ++ni) {                              \
                const int row = (wn & 1) * 64 + ni * 16 + r16;                              \
                const int o16 = row * 8 + ((kk * 4 + kb) ^ (row & 7));                      \
                bfr[ni] = *(const bf16x8*)((const char*)&lds[d][1][wn >> 1][0] + o16 * 16); \
            }                                                                               \
            __builtin_amdgcn_s_setprio(1);                                                  \
            _Pragma("unroll") for (int mi = 0; mi < 8; ++mi) {                              \
                const int row = mi * 16 + r16;                                              \
                const int o16 = row * 8 + ((kk * 4 + kb) ^ (row & 7));                      \
                bf16x8 af = *(const bf16x8*)((const char*)&lds[d][0][wm][0] + o16 * 16);    \
                _Pragma("unroll") for (int ni = 0; ni < 4; ++ni)                            \
                    acc[mi][ni] = __builtin_amdgcn_mfma_f32_16x16x32_bf16(af, bfr[ni], acc[mi][ni], 0, 0, 0); \
            }                                                                               \
            __builtin_amdgcn_s_setprio(0);                                                  \
        }                                                                                   \
    };                                                                                      \
    const int NT = (Kdim_) / 64;                                                            \
    stage(0);                                                                               \
    __syncthreads();                                                                        \
    for (int t = 0; t < NT; ++t) {                                                          \
        if (t + 1 < NT) stage(t + 1);                                                       \
        compute(t);                                                                         \
        __syncthreads();                                                                    \
    }                                                                                       \
    const int rquad = (lane >> 4) * 4;                                                      \
    const int cl    = lane & 15;

// P~ = exp(scale * qp@kp^T) bf16 + rowsum atomics.  grid (8,8,4), 512 thr.
__global__ __launch_bounds__(512, 2)
void sexp256(const ushort_t* __restrict__ qp, const ushort_t* __restrict__ kp,
             ushort_t* __restrict__ P, float* __restrict__ rowsum, float scale)
{
    int bx, by, bz;
    xcd_remap(bx, by, bz);
    const long long tM = (long long)by * 256;
    const long long tN = (long long)bx * 256;
    const int z = bz;
    const ushort_t* Ab = qp + (long long)z * 1572864;
    const ushort_t* Bb = kp + (long long)z * 1572864;

    GEMM256_CORE(Ab, 768, Bb, 768, 768)

    ushort_t* out = P + (long long)z * 4194304;
#pragma unroll
    for (int mi = 0; mi < 8; ++mi) {
        const long long r = tM + wm * 128 + mi * 16 + rquad;   // rows r..r+3
        float rs[4] = {0.f, 0.f, 0.f, 0.f};
#pragma unroll
        for (int ni = 0; ni < 4; ++ni) {
            f32x4 v = acc[mi][ni];
            const long long c = tN + wn * 64 + ni * 16 + cl;
#pragma unroll
            for (int j = 0; j < 4; ++j) {
                float p = __expf(v[j] * scale);
                ushort_t pb = f2bf(p);
                out[(r + j) * 2048 + c] = pb;
                rs[j] += bf2f(pb);     // sum exactly what PV will read
            }
        }
#pragma unroll
        for (int j = 0; j < 4; ++j) {
            float s = rs[j];
            s += __shfl_xor(s, 1, 64);
            s += __shfl_xor(s, 2, 64);
            s += __shfl_xor(s, 4, 64);
            s += __shfl_xor(s, 8, 64);
            if (cl == 0) atomicAdd(&rowsum[(long long)z * 2048 + r + j], s);
        }
    }
}

// QKV projections.  grid (3,32,3), 512 thr.
// z=0: qp = qb@Wq^T+bq [8192x768]; z=1: kp; z=2: vpT = Wv@vb^T + bv -> [768][8192]
__global__ __launch_bounds__(512, 2)
void proj256(const ushort_t* __restrict__ a0, const ushort_t* __restrict__ a1, const ushort_t* __restrict__ a2,
             const ushort_t* __restrict__ w0, const ushort_t* __restrict__ w1, const ushort_t* __restrict__ w2,
             const float* __restrict__ b0, const float* __restrict__ b1, const float* __restrict__ b2,
             ushort_t* __restrict__ dq, ushort_t* __restrict__ dk, ushort_t* __restrict__ dvT)
{
    int bx, by, bz;
    xcd_remap(bx, by, bz);
    const int z = bz;
    const long long tM = (z < 2) ? (long long)by * 256 : (long long)bx * 256;
    const long long tN = (z < 2) ? (long long)bx * 256 : (long long)by * 256;
    const ushort_t* Ab = z == 0 ? a0 : z == 1 ? a1 : w2;
    const ushort_t* Bb = z == 0 ? w0 : z == 1 ? w1 : a2;
    const float* bias  = z == 0 ? b0 : z == 1 ? b1 : b2;

    GEMM256_CORE(Ab, 768, Bb, 768, 768)

#pragma unroll
    for (int mi = 0; mi < 8; ++mi) {
        const long long r = tM + wm * 128 + mi * 16 + rquad;
        if (z < 2) {
            ushort_t* dst = z == 0 ? dq : dk;
#pragma unroll
            for (int ni = 0; ni < 4; ++ni) {
                f32x4 v = acc[mi][ni];
                const long long c = tN + wn * 64 + ni * 16 + cl;
                const float bc = bias[c];
#pragma unroll
                for (int j = 0; j < 4; ++j)
                    dst[(r + j) * 768 + c] = f2bf(v[j] + bc);
            }
        } else {
#pragma unroll
            for (int ni = 0; ni < 4; ++ni) {
                f32x4 v = acc[mi][ni];
                const long long c = tN + wn * 64 + ni * 16 + cl;
#pragma unroll
                for (int j = 0; j < 4; ++j)
                    dvT[(r + j) * 8192 + c] = f2bf(v[j] + bias[r + j]);
            }
        }
    }
}

// ============================================================================
// 128x128 / BK=32 core (round-3 proven config) for PVN and OUT.
// ============================================================================
#define M_PVN  1   // bf16 out * (1/rowsum[row]), batched
#define M_OUT  2   // fp32 out + bias

#define BM 128
#define BN 128
#define BK 32

#define GEMM_CORE(Ab_, lda_, Bb_, ldb_, Kdim_)                                              \
    __shared__ __align__(16) ushort_t lds[2][2][BM * BK];                                   \
    const int tid  = threadIdx.x;                                                           \
    const int lane = tid & 63;                                                              \
    const int wave = tid >> 6;                                                              \
    const int wr = wave >> 1, wc = wave & 1;                                                \
    f32x4 acc[4][4];                                                                        \
    _Pragma("unroll") for (int i = 0; i < 4; ++i)                                           \
        _Pragma("unroll") for (int j = 0; j < 4; ++j)                                       \
            acc[i][j] = (f32x4){0.f, 0.f, 0.f, 0.f};                                        \
    auto stage = [&](int buf, int kt) {                                                     \
        const int k0 = kt * BK;                                                             \
        _Pragma("unroll") for (int rnd = 0; rnd < 2; ++rnd) {                               \
            const int c    = tid + rnd * 256;                                               \
            const int row  = c >> 2;                                                        \
            const int slot = (c & 3) ^ (row & 3);                                           \
            const ushort_t* ga = (Ab_) + (tM + row) * (long long)(lda_) + k0 + slot * 8;    \
            const ushort_t* gb = (Bb_) + (tN + row) * (long long)(ldb_) + k0 + slot * 8;    \
            ushort_t* la = &lds[buf][0][(rnd * 256 + wave * 64) * 8];                       \
            ushort_t* lb = &lds[buf][1][(rnd * 256 + wave * 64) * 8];                       \
            __builtin_amdgcn_global_load_lds((const __attribute__((address_space(1))) void*)ga, \
                                             (__attribute__((address_space(3))) void*)la, 16, 0, 0); \
            __builtin_amdgcn_global_load_lds((const __attribute__((address_space(1))) void*)gb, \
                                             (__attribute__((address_space(3))) void*)lb, 16, 0, 0); \
        }                                                                                   \
    };                                                                                      \
    auto compute = [&](int buf) {                                                           \
        const int kb  = lane >> 4;                                                          \
        const int r16 = lane & 15;                                                          \
        bf16x8 af[4], bfr[4];                                                               \
        _Pragma("unroll") for (int mi = 0; mi < 4; ++mi) {                                  \
            const int row = wr * 64 + mi * 16 + r16;                                        \
            const int off = row * 64 + ((kb ^ (row & 3)) << 4);                             \
            af[mi] = *(const bf16x8*)((const char*)lds[buf][0] + off);                      \
        }                                                                                   \
        _Pragma("unroll") for (int ni = 0; ni < 4; ++ni) {                                  \
            const int row = wc * 64 + ni * 16 + r16;                                        \
            const int off = row * 64 + ((kb ^ (row & 3)) << 4);                             \
            bfr[ni] = *(const bf16x8*)((const char*)lds[buf][1] + off);                     \
        }                                                                                   \
        _Pragma("unroll") for (int mi = 0; mi < 4; ++mi)                                    \
            _Pragma("unroll") for (int ni = 0; ni < 4; ++ni)                                \
                acc[mi][ni] = __builtin_amdgcn_mfma_f32_16x16x32_bf16(af[mi], bfr[ni], acc[mi][ni], 0, 0, 0); \
    };                                                                                      \
    const int NT = (Kdim_) / BK;                                                            \
    stage(0, 0);                                                                            \
    __syncthreads();                                                                        \
    int cur = 0;                                                                            \
    for (int kt = 0; kt + 1 < NT; ++kt) {                                                   \
        stage(cur ^ 1, kt + 1);                                                             \
        compute(cur);                                                                       \
        __syncthreads();                                                                    \
        cur ^= 1;                                                                           \
    }                                                                                       \
    compute(cur);                                                                           \
    const int rquad = (lane >> 4) * 4;                                                      \
    const int cl    = lane & 15;

template<int MODE>
__global__ __launch_bounds__(256, 3)
void gemm_nt(const ushort_t* __restrict__ A, int lda, long long aBatch,
             const ushort_t* __restrict__ B, int ldb, long long bBatch,
             void* __restrict__ Cv, int ldc, long long cBatch,
             const float* __restrict__ bias, float* __restrict__ rowsum,
             int K)
{
    int bx, by, bz;
    xcd_remap(bx, by, bz);
    const long long tM = (long long)by * BM;
    const long long tN = (long long)bx * BN;
    const int z = bz;
    const ushort_t* Ab = A + (long long)z * aBatch;
    const ushort_t* Bb = B + (long long)z * bBatch;

    GEMM_CORE(Ab, lda, Bb, ldb, K)

#pragma unroll
    for (int mi = 0; mi < 4; ++mi) {
        const long long r = tM + wr * 64 + mi * 16 + rquad;   // rows r..r+3
        if constexpr (MODE == M_PVN) {
            ushort_t* out = (ushort_t*)Cv + (long long)z * cBatch;
            float inv[4];
#pragma unroll
            for (int j = 0; j < 4; ++j)
                inv[j] = 1.0f / rowsum[(long long)z * 2048 + r + j];
#pragma unroll
            for (int ni = 0; ni < 4; ++ni) {
                f32x4 v = acc[mi][ni];
                const long long c = tN + wc * 64 + ni * 16 + cl;
#pragma unroll
                for (int j = 0; j < 4; ++j)
                    out[(r + j) * ldc + c] = f2bf(v[j] * inv[j]);
            }
        } else {  // M_OUT
            float* out = (float*)Cv;
#pragma unroll
            for (int ni = 0; ni < 4; ++ni) {
                f32x4 v = acc[mi][ni];
                const long long c = tN + wc * 64 + ni * 16 + cl;
                const float bc = bias[c];
#pragma unroll
                for (int j = 0; j < 4; ++j)
                    out[(r + j) * ldc + c] = v[j] + bc;
            }
        }
    }
}

// ---------------- launch ----------------
extern "C" void kernel_launch(void* const* d_in, const int* in_sizes, int n_in,
                              void* d_out, int out_size, void* d_ws, size_t ws_size,
                              hipStream_t stream) {
    (void)in_sizes; (void)n_in; (void)out_size; (void)ws_size;
    const float* q  = (const float*)d_in[0];
    const float* k  = (const float*)d_in[1];
    const float* v  = (const float*)d_in[2];
    const float* Wq = (const float*)d_in[3];
    const float* bq = (const float*)d_in[4];
    const float* Wk = (const float*)d_in[5];
    const float* bk = (const float*)d_in[6];
    const float* Wv = (const float*)d_in[7];
    const float* bv = (const float*)d_in[8];
    const float* Wp = (const float*)d_in[9];
    const float* bp = (const float*)d_in[10];
    float* out = (float*)d_out;

    char* ws = (char*)d_ws;
    ushort_t* qb  = (ushort_t*)(ws);
    ushort_t* kb  = (ushort_t*)(ws + 12582912LL);
    ushort_t* vb  = (ushort_t*)(ws + 25165824LL);
    ushort_t* P   = (ushort_t*)(ws);
    float* rowsum = (float*)(ws + 33554432LL);
    ushort_t* Wqb = (ushort_t*)(ws + 67108864LL);
    ushort_t* Wkb = (ushort_t*)(ws + 68288512LL);
    ushort_t* Wvb = (ushort_t*)(ws + 69468160LL);
    ushort_t* Wpb = (ushort_t*)(ws + 70647808LL);
    ushort_t* qp  = (ushort_t*)(ws + 71827456LL);    // [8192][768] bf16
    ushort_t* kp  = (ushort_t*)(ws + 84410368LL);    // [8192][768] bf16
    ushort_t* vpT = (ushort_t*)(ws + 96993280LL);    // [768][8192] bf16
    ushort_t* Ob  = qp;                              // O overlays dead qp

    const float scale = 1.0f / sqrtf(768.0f);

    cvt_multi<<<dim3(6144, 1, 3), 256, 0, stream>>>(q, k, v, nullptr, qb, kb, vb, nullptr, 1572864);
    cvt_multi<<<dim3(576, 1, 4), 256, 0, stream>>>(Wq, Wk, Wv, Wp, Wqb, Wkb, Wvb, Wpb, 147456);

    proj256<<<dim3(3, 32, 3), 512, 0, stream>>>(qb, kb, vb, Wqb, Wkb, Wvb, bq, bk, bv, qp, kp, vpT);

    zero_f32<<<32, 256, 0, stream>>>(rowsum, 8192);

    sexp256<<<dim3(8, 8, 4), 512, 0, stream>>>(qp, kp, P, rowsum, scale);

    gemm_nt<M_PVN><<<dim3(6, 16, 4), 256, 0, stream>>>(P, 2048, 4194304, vpT, 8192, 2048,
                                                       Ob, 768, 1572864, nullptr, rowsum, 2048);

    gemm_nt<M_OUT><<<dim3(6, 64, 1), 256, 0, stream>>>(Ob, 768, 0, Wpb, 768, 0, out, 768, 0, bp, nullptr, 768);
}

// Round 9
// 168.287 us; speedup vs baseline: 1.1780x; 1.0057x over previous
//
#include <hip/hip_runtime.h>
#include <hip/hip_bf16.h>
#include <math.h>

typedef __bf16 bf16x8 __attribute__((ext_vector_type(8)));
typedef float  f32x4  __attribute__((ext_vector_type(4)));
typedef float  f32x4v __attribute__((ext_vector_type(4)));
typedef unsigned short ushort_t;
typedef ushort_t u16x4 __attribute__((ext_vector_type(4)));
typedef ushort_t u16x8 __attribute__((ext_vector_type(8)));

__device__ __forceinline__ ushort_t f2bf(float f) {
    unsigned u = __builtin_bit_cast(unsigned, f);
    u += 0x7FFFu + ((u >> 16) & 1u);
    return (ushort_t)(u >> 16);
}
__device__ __forceinline__ float bf2f(ushort_t b) {
    return __builtin_bit_cast(float, (unsigned)b << 16);
}

// XCD-aware bijective remap (m157/m204). Requires total grid % 8 == 0.
__device__ __forceinline__ void xcd_remap(int& bx, int& by, int& bz) {
    const int gx = gridDim.x, gy = gridDim.y;
    const int nwg = gx * gy * gridDim.z;
    const int lin = (blockIdx.z * gy + blockIdx.y) * gx + blockIdx.x;
    const int chunk = nwg >> 3;
    int nid = (lin & 7) * chunk + (lin >> 3);
    bx = nid % gx; nid /= gx;
    by = nid % gy; bz = nid / gy;
}

// ---------------- fp32 -> bf16 conversion (z-batched) ----------------
__global__ __launch_bounds__(256) void cvt_multi(const float* __restrict__ i0, const float* __restrict__ i1,
                                                 const float* __restrict__ i2, const float* __restrict__ i3,
                                                 ushort_t* __restrict__ o0, ushort_t* __restrict__ o1,
                                                 ushort_t* __restrict__ o2, ushort_t* __restrict__ o3, int n4) {
    const int z = blockIdx.z;
    const float* in  = z == 0 ? i0 : z == 1 ? i1 : z == 2 ? i2 : i3;
    ushort_t*    out = z == 0 ? o0 : z == 1 ? o1 : z == 2 ? o2 : o3;
    int i = blockIdx.x * 256 + threadIdx.x;
    if (i >= n4) return;
    f32x4v v = ((const f32x4v*)in)[i];
    u16x4 o = { f2bf(v.x), f2bf(v.y), f2bf(v.z), f2bf(v.w) };
    ((u16x4*)out)[i] = o;
}

__global__ __launch_bounds__(256) void zero_f32(float* __restrict__ p, int n) {
    int i = blockIdx.x * 256 + threadIdx.x;
    if (i < n) p[i] = 0.f;
}

// ============================================================================
// 256x256 / BK=64 / 8-wave / 8-PHASE core (T3+T4 counted vmcnt, T2 swizzle,
// T5 setprio). See round-7 notes; dependency audit: every LDS overwrite is
// issued >=1 closing barrier after its region's last read; vmcnt(4) at p4/p8
// completes exactly {B(t+1),A(t+1)} / {B(t+2),A(t+2)} before their reads.
// ============================================================================
#define S_BARR asm volatile("s_barrier" ::: "memory")

#define PHASE8(tt_, q_, RDB_, STC_, STKT_, STARR_, STH_, VMW_)                              \
    { bf16x8 af[2][2];                                                                      \
      if (RDB_) rd_B((tt_), bfr);                                                           \
      rd_Aq((tt_), (q_), af);                                                               \
      if (STC_) stage_h((STKT_), (STARR_), (STH_));                                         \
      S_BARR;                                                                               \
      asm volatile("s_waitcnt lgkmcnt(0)" ::: "memory");                                    \
      __builtin_amdgcn_sched_barrier(0);                                                    \
      __builtin_amdgcn_s_setprio(1);                                                        \
      _Pragma("unroll") for (int m2 = 0; m2 < 2; ++m2)                                      \
      _Pragma("unroll") for (int ni = 0; ni < 4; ++ni)                                      \
      _Pragma("unroll") for (int kk = 0; kk < 2; ++kk)                                      \
          acc[(q_)*2 + m2][ni] = __builtin_amdgcn_mfma_f32_16x16x32_bf16(                   \
              af[m2][kk], bfr[ni][kk], acc[(q_)*2 + m2][ni], 0, 0, 0);                      \
      __builtin_amdgcn_s_setprio(0);                                                        \
      VMW_;                                                                                 \
      S_BARR; }

#define GEMM256_8PH(Ab_, lda_, Bb_, ldb_, Kdim_)                                            \
    __shared__ __align__(16) ushort_t lds[2][2][2][128 * 64];                               \
    const int tid  = threadIdx.x;                                                           \
    const int lane = tid & 63;                                                              \
    const int wave = tid >> 6;                                                              \
    const int wm = wave >> 2, wn = wave & 3;                                                \
    const int r16 = lane & 15, kb = lane >> 4;                                              \
    f32x4 acc[8][4];                                                                        \
    _Pragma("unroll") for (int i_ = 0; i_ < 8; ++i_)                                        \
        _Pragma("unroll") for (int j_ = 0; j_ < 4; ++j_)                                    \
            acc[i_][j_] = (f32x4){0.f, 0.f, 0.f, 0.f};                                      \
    auto stage_h = [&](int kt, int arr, int h) {                                            \
        const int d  = kt & 1;                                                              \
        const int k0 = kt * 64;                                                             \
        _Pragma("unroll") for (int l = 0; l < 2; ++l) {                                     \
            const int idx = l * 512 + tid;                                                  \
            const int row = idx >> 3, sl = idx & 7;                                         \
            const int ssrc = sl ^ (row & 7);                                                \
            const long long grow = h * 128 + row;                                           \
            const ushort_t* g = (arr == 0)                                                  \
                ? (Ab_) + (tM + grow) * (long long)(lda_) + k0 + ssrc * 8                   \
                : (Bb_) + (tN + grow) * (long long)(ldb_) + k0 + ssrc * 8;                  \
            __builtin_amdgcn_global_load_lds((const __attribute__((address_space(1))) void*)g, \
                (__attribute__((address_space(3))) void*)&lds[d][arr][h][idx * 8], 16, 0, 0); \
        } };                                                                                \
    auto rd_B = [&](int kt, bf16x8 (&bfr_)[4][2]) {                                         \
        const int d = kt & 1;                                                               \
        _Pragma("unroll") for (int ni = 0; ni < 4; ++ni)                                    \
        _Pragma("unroll") for (int kk = 0; kk < 2; ++kk) {                                  \
            const int row = (wn & 1) * 64 + ni * 16 + r16;                                  \
            const int o16 = row * 8 + ((kk * 4 + kb) ^ (row & 7));                          \
            bfr_[ni][kk] = *(const bf16x8*)((const char*)&lds[d][1][wn >> 1][0] + o16 * 16);\
        } };                                                                                \
    auto rd_Aq = [&](int kt, int q, bf16x8 (&af_)[2][2]) {                                  \
        const int d = kt & 1;                                                               \
        _Pragma("unroll") for (int m2 = 0; m2 < 2; ++m2)                                    \
        _Pragma("unroll") for (int kk = 0; kk < 2; ++kk) {                                  \
            const int row = (q * 2 + m2) * 16 + r16;                                        \
            const int o16 = row * 8 + ((kk * 4 + kb) ^ (row & 7));                          \
            af_[m2][kk] = *(const bf16x8*)((const char*)&lds[d][0][wm][0] + o16 * 16);      \
        } };                                                                                \
    const int NT = (Kdim_) / 64;                                                            \
    /* prologue: B(0), A(0), B(1); allow B(1) (4 instr) outstanding */                      \
    stage_h(0, 1, 0); stage_h(0, 1, 1);                                                     \
    stage_h(0, 0, 0); stage_h(0, 0, 1);                                                     \
    stage_h(1, 1, 0); stage_h(1, 1, 1);                                                     \
    asm volatile("s_waitcnt vmcnt(4)" ::: "memory");                                        \
    S_BARR;                                                                                 \
    _Pragma("unroll 1") for (int it = 0; it < NT / 2; ++it) {                               \
        const int t = 2 * it;                                                               \
        const bool more = (t + 2 < NT);                                                     \
        bf16x8 bfr[4][2];                                                                   \
        PHASE8(t,     0, true,  true, t + 1, 0, 0, )                                        \
        PHASE8(t,     1, false, true, t + 1, 0, 1, )                                        \
        PHASE8(t,     2, false, more, t + 2, 1, 0, )                                        \
        PHASE8(t,     3, false, more, t + 2, 1, 1,                                          \
               if (more) asm volatile("s_waitcnt vmcnt(4)" ::: "memory");                   \
               else      asm volatile("s_waitcnt vmcnt(0)" ::: "memory"))                   \
        PHASE8(t + 1, 0, true,  more, t + 2, 0, 0, )                                        \
        PHASE8(t + 1, 1, false, more, t + 2, 0, 1, )                                        \
        PHASE8(t + 1, 2, false, more, t + 3, 1, 0, )                                        \
        PHASE8(t + 1, 3, false, more, t + 3, 1, 1,                                          \
               if (more) asm volatile("s_waitcnt vmcnt(4)" ::: "memory"))                   \
    }                                                                                       \
    const int rquad = (lane >> 4) * 4;                                                      \
    const int cl    = lane & 15;

// ---------------- Q,K projections: 8-phase, grid (3,32,2) = 192 blocks ------
__global__ __launch_bounds__(512, 2)
void projqk8(const ushort_t* __restrict__ qin, const ushort_t* __restrict__ kin,
             const ushort_t* __restrict__ Wqb, const ushort_t* __restrict__ Wkb,
             const float* __restrict__ bqv, const float* __restrict__ bkv,
             ushort_t* __restrict__ dq, ushort_t* __restrict__ dk)
{
    int bx, by, bz;
    xcd_remap(bx, by, bz);
    const int z = bz;
    const long long tM = (long long)by * 256;
    const long long tN = (long long)bx * 256;
    const ushort_t* Ab = z ? kin : qin;
    const ushort_t* Bb = z ? Wkb : Wqb;
    const float* bias  = z ? bkv : bqv;
    ushort_t* dst      = z ? dk : dq;

    GEMM256_8PH(Ab, 768, Bb, 768, 768)

#pragma unroll
    for (int mi = 0; mi < 8; ++mi) {
        const long long r = tM + wm * 128 + mi * 16 + rquad;
#pragma unroll
        for (int ni = 0; ni < 4; ++ni) {
            f32x4 v = acc[mi][ni];
            const long long c = tN + wn * 64 + ni * 16 + cl;
            const float bc = bias[c];
#pragma unroll
            for (int j = 0; j < 4; ++j)
                dst[(r + j) * 768 + c] = f2bf(v[j] + bc);
        }
    }
}

// ------ fused: sexp (blocks 0..255) + V-projection (blocks 256..351) --------
// sexp: P~ = exp(scale * qp@kp^T) bf16 + rowsum atomics (per batch z).
// projV: vpT = Wv@vb^T + bv(row) -> [768][8192], coalesced store.
// WORKSPACE CONTRACT: P/rowsum/vpT regions are fully disjoint from vb/Wvb/qp/kp
// (the round-8 NaN was P+rowsum overlaying vb while is_pv blocks read it).
__global__ __launch_bounds__(512, 2)
void sexp_pv8(const ushort_t* __restrict__ qp, const ushort_t* __restrict__ kp,
              const ushort_t* __restrict__ Wvb, const ushort_t* __restrict__ vin,
              const float* __restrict__ bvv,
              ushort_t* __restrict__ P, float* __restrict__ rowsum,
              ushort_t* __restrict__ dvT, float scale)
{
    int bx, by, bz;
    xcd_remap(bx, by, bz);
    const int wid = bx;
    const bool is_pv = wid >= 256;
    long long tM, tN;
    const ushort_t *Ab, *Bb;
    int z = 0;
    if (!is_pv) {
        z = wid >> 6;
        const int w2 = wid & 63;
        tM = (long long)(w2 >> 3) * 256;
        tN = (long long)(w2 & 7) * 256;
        Ab = qp + (long long)z * 1572864;
        Bb = kp + (long long)z * 1572864;
    } else {
        const int pv = wid - 256;
        tM = (long long)(pv >> 5) * 256;     // feature rows (768 -> 3 tiles)
        tN = (long long)(pv & 31) * 256;     // token cols  (8192 -> 32 tiles)
        Ab = Wvb;
        Bb = vin;
    }

    GEMM256_8PH(Ab, 768, Bb, 768, 768)

    if (!is_pv) {
        ushort_t* out = P + (long long)z * 4194304;
#pragma unroll
        for (int mi = 0; mi < 8; ++mi) {
            const long long r = tM + wm * 128 + mi * 16 + rquad;
            float rs[4] = {0.f, 0.f, 0.f, 0.f};
#pragma unroll
            for (int ni = 0; ni < 4; ++ni) {
                f32x4 v = acc[mi][ni];
                const long long c = tN + wn * 64 + ni * 16 + cl;
#pragma unroll
                for (int j = 0; j < 4; ++j) {
                    float p = __expf(v[j] * scale);
                    ushort_t pb = f2bf(p);
                    out[(r + j) * 2048 + c] = pb;
                    rs[j] += bf2f(pb);     // sum exactly what PV will read
                }
            }
#pragma unroll
            for (int j = 0; j < 4; ++j) {
                float s = rs[j];
                s += __shfl_xor(s, 1, 64);
                s += __shfl_xor(s, 2, 64);
                s += __shfl_xor(s, 4, 64);
                s += __shfl_xor(s, 8, 64);
                if (cl == 0) atomicAdd(&rowsum[(long long)z * 2048 + r + j], s);
            }
        }
    } else {
#pragma unroll
        for (int mi = 0; mi < 8; ++mi) {
            const long long r = tM + wm * 128 + mi * 16 + rquad;
#pragma unroll
            for (int ni = 0; ni < 4; ++ni) {
                f32x4 v = acc[mi][ni];
                const long long c = tN + wn * 64 + ni * 16 + cl;
#pragma unroll
                for (int j = 0; j < 4; ++j)
                    dvT[(r + j) * 8192 + c] = f2bf(v[j] + bvv[r + j]);
            }
        }
    }
}

// ============================================================================
// 128x128 / BK=32 core (round-3 proven config) for PVN and OUT.
// ============================================================================
#define M_PVN  1   // bf16 out * (1/rowsum[row]), batched
#define M_OUT  2   // fp32 out + bias

#define BM 128
#define BN 128
#define BK 32

#define GEMM_CORE(Ab_, lda_, Bb_, ldb_, Kdim_)                                              \
    __shared__ __align__(16) ushort_t lds[2][2][BM * BK];                                   \
    const int tid  = threadIdx.x;                                                           \
    const int lane = tid & 63;                                                              \
    const int wave = tid >> 6;                                                              \
    const int wr = wave >> 1, wc = wave & 1;                                                \
    f32x4 acc[4][4];                                                                        \
    _Pragma("unroll") for (int i = 0; i < 4; ++i)                                           \
        _Pragma("unroll") for (int j = 0; j < 4; ++j)                                       \
            acc[i][j] = (f32x4){0.f, 0.f, 0.f, 0.f};                                        \
    auto stage = [&](int buf, int kt) {                                                     \
        const int k0 = kt * BK;                                                             \
        _Pragma("unroll") for (int rnd = 0; rnd < 2; ++rnd) {                               \
            const int c    = tid + rnd * 256;                                               \
            const int row  = c >> 2;                                                        \
            const int slot = (c & 3) ^ (row & 3);                                           \
            const ushort_t* ga = (Ab_) + (tM + row) * (long long)(lda_) + k0 + slot * 8;    \
            const ushort_t* gb = (Bb_) + (tN + row) * (long long)(ldb_) + k0 + slot * 8;    \
            ushort_t* la = &lds[buf][0][(rnd * 256 + wave * 64) * 8];                       \
            ushort_t* lb = &lds[buf][1][(rnd * 256 + wave * 64) * 8];                       \
            __builtin_amdgcn_global_load_lds((const __attribute__((address_space(1))) void*)ga, \
                                             (__attribute__((address_space(3))) void*)la, 16, 0, 0); \
            __builtin_amdgcn_global_load_lds((const __attribute__((address_space(1))) void*)gb, \
                                             (__attribute__((address_space(3))) void*)lb, 16, 0, 0); \
        }                                                                                   \
    };                                                                                      \
    auto compute = [&](int buf) {                                                           \
        const int kb  = lane >> 4;                                                          \
        const int r16 = lane & 15;                                                          \
        bf16x8 af[4], bfr[4];                                                               \
        _Pragma("unroll") for (int mi = 0; mi < 4; ++mi) {                                  \
            const int row = wr * 64 + mi * 16 + r16;                                        \
            const int off = row * 64 + ((kb ^ (row & 3)) << 4);                             \
            af[mi] = *(const bf16x8*)((const char*)lds[buf][0] + off);                      \
        }                                                                                   \
        _Pragma("unroll") for (int ni = 0; ni < 4; ++ni) {                                  \
            const int row = wc * 64 + ni * 16 + r16;                                        \
            const int off = row * 64 + ((kb ^ (row & 3)) << 4);                             \
            bfr[ni] = *(const bf16x8*)((const char*)lds[buf][1] + off);                     \
        }                                                                                   \
        _Pragma("unroll") for (int mi = 0; mi < 4; ++mi)                                    \
            _Pragma("unroll") for (int ni = 0; ni < 4; ++ni)                                \
                acc[mi][ni] = __builtin_amdgcn_mfma_f32_16x16x32_bf16(af[mi], bfr[ni], acc[mi][ni], 0, 0, 0); \
    };                                                                                      \
    const int NT = (Kdim_) / BK;                                                            \
    stage(0, 0);                                                                            \
    __syncthreads();                                                                        \
    int cur = 0;                                                                            \
    for (int kt = 0; kt + 1 < NT; ++kt) {                                                   \
        stage(cur ^ 1, kt + 1);                                                             \
        compute(cur);                                                                       \
        __syncthreads();                                                                    \
        cur ^= 1;                                                                           \
    }                                                                                       \
    compute(cur);                                                                           \
    const int rquad = (lane >> 4) * 4;                                                      \
    const int cl    = lane & 15;

template<int MODE>
__global__ __launch_bounds__(256, 3)
void gemm_nt(const ushort_t* __restrict__ A, int lda, long long aBatch,
             const ushort_t* __restrict__ B, int ldb, long long bBatch,
             void* __restrict__ Cv, int ldc, long long cBatch,
             const float* __restrict__ bias, float* __restrict__ rowsum,
             int K)
{
    int bx, by, bz;
    xcd_remap(bx, by, bz);
    const long long tM = (long long)by * BM;
    const long long tN = (long long)bx * BN;
    const int z = bz;
    const ushort_t* Ab = A + (long long)z * aBatch;
    const ushort_t* Bb = B + (long long)z * bBatch;

    GEMM_CORE(Ab, lda, Bb, ldb, K)

#pragma unroll
    for (int mi = 0; mi < 4; ++mi) {
        const long long r = tM + wr * 64 + mi * 16 + rquad;   // rows r..r+3
        if constexpr (MODE == M_PVN) {
            ushort_t* out = (ushort_t*)Cv + (long long)z * cBatch;
            float inv[4];
#pragma unroll
            for (int j = 0; j < 4; ++j)
                inv[j] = 1.0f / rowsum[(long long)z * 2048 + r + j];
#pragma unroll
            for (int ni = 0; ni < 4; ++ni) {
                f32x4 v = acc[mi][ni];
                const long long c = tN + wc * 64 + ni * 16 + cl;
#pragma unroll
                for (int j = 0; j < 4; ++j)
                    out[(r + j) * ldc + c] = f2bf(v[j] * inv[j]);
            }
        } else {  // M_OUT
            float* out = (float*)Cv;
#pragma unroll
            for (int ni = 0; ni < 4; ++ni) {
                f32x4 v = acc[mi][ni];
                const long long c = tN + wc * 64 + ni * 16 + cl;
                const float bc = bias[c];
#pragma unroll
                for (int j = 0; j < 4; ++j)
                    out[(r + j) * ldc + c] = v[j] + bc;
            }
        }
    }
}

// ---------------- launch ----------------
extern "C" void kernel_launch(void* const* d_in, const int* in_sizes, int n_in,
                              void* d_out, int out_size, void* d_ws, size_t ws_size,
                              hipStream_t stream) {
    (void)in_sizes; (void)n_in; (void)out_size; (void)ws_size;
    const float* q  = (const float*)d_in[0];
    const float* k  = (const float*)d_in[1];
    const float* v  = (const float*)d_in[2];
    const float* Wq = (const float*)d_in[3];
    const float* bq = (const float*)d_in[4];
    const float* Wk = (const float*)d_in[5];
    const float* bk = (const float*)d_in[6];
    const float* Wv = (const float*)d_in[7];
    const float* bv = (const float*)d_in[8];
    const float* Wp = (const float*)d_in[9];
    const float* bp = (const float*)d_in[10];
    float* out = (float*)d_out;

    // ---- workspace layout (88.6 MB total; NO live-overlay anywhere) ----
    // vb [0,12.6M) lives through sexp_pv8. qb/kb die after projqk8; P (32MB)
    // overlays qb+kb+reserved gap [12.6M,46.1M). Everything else above 44MB.
    char* ws = (char*)d_ws;
    ushort_t* vb  = (ushort_t*)(ws);                 // [0,      12582912)
    ushort_t* qb  = (ushort_t*)(ws + 12582912LL);    // [12.6M,  25165824)
    ushort_t* kb  = (ushort_t*)(ws + 25165824LL);    // [25.2M,  37748736)
    ushort_t* P   = (ushort_t*)(ws + 12582912LL);    // [12.6M,  46137344)  overlays dead qb,kb + gap
    ushort_t* Wqb = (ushort_t*)(ws + 46137344LL);
    ushort_t* Wkb = (ushort_t*)(ws + 47316992LL);
    ushort_t* Wvb = (ushort_t*)(ws + 48496640LL);
    ushort_t* Wpb = (ushort_t*)(ws + 49676288LL);
    ushort_t* qp  = (ushort_t*)(ws + 50855936LL);    // [8192][768] bf16
    ushort_t* kp  = (ushort_t*)(ws + 63438848LL);    // [8192][768] bf16
    ushort_t* vpT = (ushort_t*)(ws + 76021760LL);    // [768][8192] bf16
    float* rowsum = (float*)(ws + 88604672LL);       // 8192 f32
    ushort_t* Ob  = qp;                              // O overlays dead qp

    const float scale = 1.0f / sqrtf(768.0f);

    cvt_multi<<<dim3(6144, 1, 3), 256, 0, stream>>>(q, k, v, nullptr, qb, kb, vb, nullptr, 1572864);
    cvt_multi<<<dim3(576, 1, 4), 256, 0, stream>>>(Wq, Wk, Wv, Wp, Wqb, Wkb, Wvb, Wpb, 147456);

    // Q,K projections (192 blocks, single occupancy round)
    projqk8<<<dim3(3, 32, 2), 512, 0, stream>>>(qb, kb, Wqb, Wkb, bq, bk, qp, kp);

    zero_f32<<<32, 256, 0, stream>>>(rowsum, 8192);

    // fused: exp(QK^T) + rowsum (256 tiles) and V-projection (96 tiles)
    sexp_pv8<<<dim3(352, 1, 1), 512, 0, stream>>>(qp, kp, Wvb, vb, bv, P, rowsum, vpT, scale);

    gemm_nt<M_PVN><<<dim3(6, 16, 4), 256, 0, stream>>>(P, 2048, 4194304, vpT, 8192, 2048,
                                                       Ob, 768, 1572864, nullptr, rowsum, 2048);

    gemm_nt<M_OUT><<<dim3(6, 64, 1), 256, 0, stream>>>(Ob, 768, 0, Wpb, 768, 0, out, 768, 0, bp, nullptr, 768);
}

// Round 10
// 167.618 us; speedup vs baseline: 1.1827x; 1.0040x over previous
//
#include <hip/hip_runtime.h>
#include <hip/hip_bf16.h>
#include <math.h>

typedef __bf16 bf16x8 __attribute__((ext_vector_type(8)));
typedef float  f32x4  __attribute__((ext_vector_type(4)));
typedef float  f32x4v __attribute__((ext_vector_type(4)));
typedef unsigned short ushort_t;
typedef ushort_t u16x4 __attribute__((ext_vector_type(4)));
typedef ushort_t u16x8 __attribute__((ext_vector_type(8)));

__device__ __forceinline__ ushort_t f2bf(float f) {
    unsigned u = __builtin_bit_cast(unsigned, f);
    u += 0x7FFFu + ((u >> 16) & 1u);
    return (ushort_t)(u >> 16);
}
__device__ __forceinline__ float bf2f(ushort_t b) {
    return __builtin_bit_cast(float, (unsigned)b << 16);
}

// XCD-aware bijective remap (m157/m204). Requires total grid % 8 == 0.
__device__ __forceinline__ void xcd_remap(int& bx, int& by, int& bz) {
    const int gx = gridDim.x, gy = gridDim.y;
    const int nwg = gx * gy * gridDim.z;
    const int lin = (blockIdx.z * gy + blockIdx.y) * gx + blockIdx.x;
    const int chunk = nwg >> 3;
    int nid = (lin & 7) * chunk + (lin >> 3);
    bx = nid % gx; nid /= gx;
    by = nid % gy; bz = nid / gy;
}

// ---------------- fp32 -> bf16 conversion (z-batched) ----------------
__global__ __launch_bounds__(256) void cvt_multi(const float* __restrict__ i0, const float* __restrict__ i1,
                                                 const float* __restrict__ i2, const float* __restrict__ i3,
                                                 ushort_t* __restrict__ o0, ushort_t* __restrict__ o1,
                                                 ushort_t* __restrict__ o2, ushort_t* __restrict__ o3, int n4) {
    const int z = blockIdx.z;
    const float* in  = z == 0 ? i0 : z == 1 ? i1 : z == 2 ? i2 : i3;
    ushort_t*    out = z == 0 ? o0 : z == 1 ? o1 : z == 2 ? o2 : o3;
    int i = blockIdx.x * 256 + threadIdx.x;
    if (i >= n4) return;
    f32x4v v = ((const f32x4v*)in)[i];
    u16x4 o = { f2bf(v.x), f2bf(v.y), f2bf(v.z), f2bf(v.w) };
    ((u16x4*)out)[i] = o;
}

__global__ __launch_bounds__(256) void zero_f32(float* __restrict__ p, int n) {
    int i = blockIdx.x * 256 + threadIdx.x;
    if (i < n) p[i] = 0.f;
}

// ============================================================================
// 256x256 / BK=64 / 8-wave / 4-PHASE-per-K-tile deep-pipelined core.
// Fully unrolled (NT compile-time) -> all guards/addresses constexpr.
// Per iter t: p1{rd_B(t)+rd_A(t,q0) | stage A(t+1)h0}, p2{rd_A q1 | A(t+1)h1},
// p3{rd_A q2 | B(t+2)h0}, p4{rd_A q3 | B(t+2)h1, vmcnt(4)}. Each phase:
// reads/stage -> BARR -> lgkm0+schedbar -> setprio(1) 16 MFMA setprio(0)
// [-> p4 wait] -> BARR. Audited: B(t) waited 4-5 phases after issue, A(t)
// 2-3 phases; every LDS overwrite >=1 closing barrier after last read;
// wait-before-barrier/read-after-barrier gives cross-wave safety.
// ============================================================================
#define S_BARR   asm volatile("s_barrier" ::: "memory")
#define LGKM0_SB asm volatile("s_waitcnt lgkmcnt(0)" ::: "memory"); __builtin_amdgcn_sched_barrier(0)

#define MFMA16(q_)                                                                          \
    __builtin_amdgcn_s_setprio(1);                                                          \
    _Pragma("unroll") for (int m2 = 0; m2 < 2; ++m2)                                        \
    _Pragma("unroll") for (int ni = 0; ni < 4; ++ni)                                        \
    _Pragma("unroll") for (int kk = 0; kk < 2; ++kk)                                        \
        acc[(q_)*2 + m2][ni] = __builtin_amdgcn_mfma_f32_16x16x32_bf16(                     \
            af[m2][kk], bfr[ni][kk], acc[(q_)*2 + m2][ni], 0, 0, 0);                        \
    __builtin_amdgcn_s_setprio(0)

#define GEMM256_4PH(Ab_, lda_, Bb_, ldb_, NTv)                                              \
    __shared__ __align__(16) ushort_t lds[2][2][2][128 * 64];                               \
    const int tid  = threadIdx.x;                                                           \
    const int lane = tid & 63;                                                              \
    const int wave = tid >> 6;                                                              \
    const int wm = wave >> 2, wn = wave & 3;                                                \
    const int r16 = lane & 15, kb = lane >> 4;                                              \
    f32x4 acc[8][4];                                                                        \
    _Pragma("unroll") for (int i_ = 0; i_ < 8; ++i_)                                        \
        _Pragma("unroll") for (int j_ = 0; j_ < 4; ++j_)                                    \
            acc[i_][j_] = (f32x4){0.f, 0.f, 0.f, 0.f};                                      \
    auto stage_h = [&](int kt, int arr, int h) {                                            \
        const int d  = kt & 1;                                                              \
        const int k0 = kt * 64;                                                             \
        _Pragma("unroll") for (int l = 0; l < 2; ++l) {                                     \
            const int idx = l * 512 + tid;                                                  \
            const int row = idx >> 3, sl = idx & 7;                                         \
            const int ssrc = sl ^ (row & 7);                                                \
            const long long grow = h * 128 + row;                                           \
            const ushort_t* g = (arr == 0)                                                  \
                ? (Ab_) + (tM + grow) * (long long)(lda_) + k0 + ssrc * 8                   \
                : (Bb_) + (tN + grow) * (long long)(ldb_) + k0 + ssrc * 8;                  \
            __builtin_amdgcn_global_load_lds((const __attribute__((address_space(1))) void*)g, \
                (__attribute__((address_space(3))) void*)&lds[d][arr][h][idx * 8], 16, 0, 0); \
        } };                                                                                \
    auto rd_B = [&](int kt, bf16x8 (&bfr_)[4][2]) {                                         \
        const int d = kt & 1;                                                               \
        _Pragma("unroll") for (int ni = 0; ni < 4; ++ni)                                    \
        _Pragma("unroll") for (int kk = 0; kk < 2; ++kk) {                                  \
            const int row = (wn & 1) * 64 + ni * 16 + r16;                                  \
            const int o16 = row * 8 + ((kk * 4 + kb) ^ (row & 7));                          \
            bfr_[ni][kk] = *(const bf16x8*)((const char*)&lds[d][1][wn >> 1][0] + o16 * 16);\
        } };                                                                                \
    auto rd_Aq = [&](int kt, int q, bf16x8 (&af_)[2][2]) {                                  \
        const int d = kt & 1;                                                               \
        _Pragma("unroll") for (int m2 = 0; m2 < 2; ++m2)                                    \
        _Pragma("unroll") for (int kk = 0; kk < 2; ++kk) {                                  \
            const int row = (q * 2 + m2) * 16 + r16;                                        \
            const int o16 = row * 8 + ((kk * 4 + kb) ^ (row & 7));                          \
            af_[m2][kk] = *(const bf16x8*)((const char*)&lds[d][0][wm][0] + o16 * 16);      \
        } };                                                                                \
    /* prologue: B(0), A(0), B(1); wait B(0)+A(0); B(1) stays in flight */                  \
    stage_h(0, 1, 0); stage_h(0, 1, 1);                                                     \
    stage_h(0, 0, 0); stage_h(0, 0, 1);                                                     \
    stage_h(1, 1, 0); stage_h(1, 1, 1);                                                     \
    asm volatile("s_waitcnt vmcnt(4)" ::: "memory");                                        \
    S_BARR;                                                                                 \
    _Pragma("unroll") for (int t = 0; t < (NTv); ++t) {                                     \
        bf16x8 bfr[4][2];                                                                   \
        { bf16x8 af[2][2];                                                                  \
          rd_B(t, bfr); rd_Aq(t, 0, af);                                                    \
          if (t + 1 < (NTv)) stage_h(t + 1, 0, 0);                                          \
          S_BARR; LGKM0_SB; MFMA16(0); S_BARR; }                                            \
        { bf16x8 af[2][2];                                                                  \
          rd_Aq(t, 1, af);                                                                  \
          if (t + 1 < (NTv)) stage_h(t + 1, 0, 1);                                          \
          S_BARR; LGKM0_SB; MFMA16(1); S_BARR; }                                            \
        { bf16x8 af[2][2];                                                                  \
          rd_Aq(t, 2, af);                                                                  \
          if (t + 2 < (NTv)) stage_h(t + 2, 1, 0);                                          \
          S_BARR; LGKM0_SB; MFMA16(2); S_BARR; }                                            \
        { bf16x8 af[2][2];                                                                  \
          rd_Aq(t, 3, af);                                                                  \
          if (t + 2 < (NTv)) stage_h(t + 2, 1, 1);                                          \
          S_BARR; LGKM0_SB; MFMA16(3);                                                      \
          if (t == (NTv) - 2)      { asm volatile("s_waitcnt vmcnt(0)" ::: "memory"); }     \
          else if (t < (NTv) - 2)  { asm volatile("s_waitcnt vmcnt(4)" ::: "memory"); }     \
          S_BARR; }                                                                         \
    }                                                                                       \
    const int rquad = (lane >> 4) * 4;                                                      \
    const int cl    = lane & 15;

// ---------------- Q,K projections: 4ph, grid (3,32,2) = 192 blocks ----------
__global__ __launch_bounds__(512, 2)
void projqk4(const ushort_t* __restrict__ qin, const ushort_t* __restrict__ kin,
             const ushort_t* __restrict__ Wqb, const ushort_t* __restrict__ Wkb,
             const float* __restrict__ bqv, const float* __restrict__ bkv,
             ushort_t* __restrict__ dq, ushort_t* __restrict__ dk)
{
    int bx, by, bz;
    xcd_remap(bx, by, bz);
    const int z = bz;
    const long long tM = (long long)by * 256;
    const long long tN = (long long)bx * 256;
    const ushort_t* Ab = z ? kin : qin;
    const ushort_t* Bb = z ? Wkb : Wqb;
    const float* bias  = z ? bkv : bqv;
    ushort_t* dst      = z ? dk : dq;

    GEMM256_4PH(Ab, 768, Bb, 768, 12)

#pragma unroll
    for (int mi = 0; mi < 8; ++mi) {
        const long long r = tM + wm * 128 + mi * 16 + rquad;
#pragma unroll
        for (int ni = 0; ni < 4; ++ni) {
            f32x4 v = acc[mi][ni];
            const long long c = tN + wn * 64 + ni * 16 + cl;
            const float bc = bias[c];
#pragma unroll
            for (int j = 0; j < 4; ++j)
                dst[(r + j) * 768 + c] = f2bf(v[j] + bc);
        }
    }
}

// ---------------- sexp: P~ = exp(scale*qp@kp^T) + rowsum, 256 blocks --------
__global__ __launch_bounds__(512, 2)
void sexp4(const ushort_t* __restrict__ qp, const ushort_t* __restrict__ kp,
           ushort_t* __restrict__ P, float* __restrict__ rowsum, float scale)
{
    int bx, by, bz;
    xcd_remap(bx, by, bz);
    const long long tM = (long long)by * 256;
    const long long tN = (long long)bx * 256;
    const int z = bz;
    const ushort_t* Ab = qp + (long long)z * 1572864;
    const ushort_t* Bb = kp + (long long)z * 1572864;

    GEMM256_4PH(Ab, 768, Bb, 768, 12)

    ushort_t* out = P + (long long)z * 4194304;
#pragma unroll
    for (int mi = 0; mi < 8; ++mi) {
        const long long r = tM + wm * 128 + mi * 16 + rquad;
        float rs[4] = {0.f, 0.f, 0.f, 0.f};
#pragma unroll
        for (int ni = 0; ni < 4; ++ni) {
            f32x4 v = acc[mi][ni];
            const long long c = tN + wn * 64 + ni * 16 + cl;
#pragma unroll
            for (int j = 0; j < 4; ++j) {
                float p = __expf(v[j] * scale);
                ushort_t pb = f2bf(p);
                out[(r + j) * 2048 + c] = pb;
                rs[j] += bf2f(pb);     // sum exactly what PV will read
            }
        }
#pragma unroll
        for (int j = 0; j < 4; ++j) {
            float s = rs[j];
            s += __shfl_xor(s, 1, 64);
            s += __shfl_xor(s, 2, 64);
            s += __shfl_xor(s, 4, 64);
            s += __shfl_xor(s, 8, 64);
            if (cl == 0) atomicAdd(&rowsum[(long long)z * 2048 + r + j], s);
        }
    }
}

// ------ fused: V-projection (blocks 0..95) + cvt of q,k (blocks 96..255) ----
// V-proj: vpT = Wv@vb^T + bv(row) -> [768][8192]. cvt: fp32->bf16 grid-stride.
__global__ __launch_bounds__(512, 2)
void vprojcvt(const ushort_t* __restrict__ wv_, const ushort_t* __restrict__ vb_,
              const float* __restrict__ bv_, ushort_t* __restrict__ dvT_,
              const float* __restrict__ qf_, const float* __restrict__ kf_,
              ushort_t* __restrict__ qb_, ushort_t* __restrict__ kb_)
{
    if (blockIdx.x < 96) {
        const int id = blockIdx.x;
        const long long tM = (long long)(id % 3) * 256;    // feature rows (768)
        const long long tN = (long long)(id / 3) * 256;    // token cols (8192)
        const ushort_t* Ab = wv_;
        const ushort_t* Bb = vb_;

        GEMM256_4PH(Ab, 768, Bb, 768, 12)

#pragma unroll
        for (int mi = 0; mi < 8; ++mi) {
            const long long r = tM + wm * 128 + mi * 16 + rquad;
#pragma unroll
            for (int ni = 0; ni < 4; ++ni) {
                f32x4 v = acc[mi][ni];
                const long long c = tN + wn * 64 + ni * 16 + cl;
#pragma unroll
                for (int j = 0; j < 4; ++j)
                    dvT_[(r + j) * 8192 + c] = f2bf(v[j] + bv_[r + j]);
            }
        }
    } else {
        const long long stride = 160LL * 512;
        for (long long i = (long long)(blockIdx.x - 96) * 512 + threadIdx.x;
             i < 2LL * 1572864; i += stride) {
            const float* src; ushort_t* dst; long long off;
            if (i < 1572864) { src = qf_; dst = qb_; off = i; }
            else             { src = kf_; dst = kb_; off = i - 1572864; }
            f32x4v v4 = ((const f32x4v*)src)[off];
            u16x4 o = { f2bf(v4.x), f2bf(v4.y), f2bf(v4.z), f2bf(v4.w) };
            ((u16x4*)dst)[off] = o;
        }
    }
}

// ============================================================================
// 128x128 / BK=32 core (round-3 proven config) for PVN and OUT.
// ============================================================================
#define M_PVN  1   // bf16 out * (1/rowsum[row]), batched
#define M_OUT  2   // fp32 out + bias

#define BM 128
#define BN 128
#define BK 32

#define GEMM_CORE(Ab_, lda_, Bb_, ldb_, Kdim_)                                              \
    __shared__ __align__(16) ushort_t lds[2][2][BM * BK];                                   \
    const int tid  = threadIdx.x;                                                           \
    const int lane = tid & 63;                                                              \
    const int wave = tid >> 6;                                                              \
    const int wr = wave >> 1, wc = wave & 1;                                                \
    f32x4 acc[4][4];                                                                        \
    _Pragma("unroll") for (int i = 0; i < 4; ++i)                                           \
        _Pragma("unroll") for (int j = 0; j < 4; ++j)                                       \
            acc[i][j] = (f32x4){0.f, 0.f, 0.f, 0.f};                                        \
    auto stage = [&](int buf, int kt) {                                                     \
        const int k0 = kt * BK;                                                             \
        _Pragma("unroll") for (int rnd = 0; rnd < 2; ++rnd) {                               \
            const int c    = tid + rnd * 256;                                               \
            const int row  = c >> 2;                                                        \
            const int slot = (c & 3) ^ (row & 3);                                           \
            const ushort_t* ga = (Ab_) + (tM + row) * (long long)(lda_) + k0 + slot * 8;    \
            const ushort_t* gb = (Bb_) + (tN + row) * (long long)(ldb_) + k0 + slot * 8;    \
            ushort_t* la = &lds[buf][0][(rnd * 256 + wave * 64) * 8];                       \
            ushort_t* lb = &lds[buf][1][(rnd * 256 + wave * 64) * 8];                       \
            __builtin_amdgcn_global_load_lds((const __attribute__((address_space(1))) void*)ga, \
                                             (__attribute__((address_space(3))) void*)la, 16, 0, 0); \
            __builtin_amdgcn_global_load_lds((const __attribute__((address_space(1))) void*)gb, \
                                             (__attribute__((address_space(3))) void*)lb, 16, 0, 0); \
        }                                                                                   \
    };                                                                                      \
    auto compute = [&](int buf) {                                                           \
        const int kb  = lane >> 4;                                                          \
        const int r16 = lane & 15;                                                          \
        bf16x8 af[4], bfr[4];                                                               \
        _Pragma("unroll") for (int mi = 0; mi < 4; ++mi) {                                  \
            const int row = wr * 64 + mi * 16 + r16;                                        \
            const int off = row * 64 + ((kb ^ (row & 3)) << 4);                             \
            af[mi] = *(const bf16x8*)((const char*)lds[buf][0] + off);                      \
        }                                                                                   \
        _Pragma("unroll") for (int ni = 0; ni < 4; ++ni) {                                  \
            const int row = wc * 64 + ni * 16 + r16;                                        \
            const int off = row * 64 + ((kb ^ (row & 3)) << 4);                             \
            bfr[ni] = *(const bf16x8*)((const char*)lds[buf][1] + off);                     \
        }                                                                                   \
        _Pragma("unroll") for (int mi = 0; mi < 4; ++mi)                                    \
            _Pragma("unroll") for (int ni = 0; ni < 4; ++ni)                                \
                acc[mi][ni] = __builtin_amdgcn_mfma_f32_16x16x32_bf16(af[mi], bfr[ni], acc[mi][ni], 0, 0, 0); \
    };                                                                                      \
    const int NT = (Kdim_) / BK;                                                            \
    stage(0, 0);                                                                            \
    __syncthreads();                                                                        \
    int cur = 0;                                                                            \
    for (int kt = 0; kt + 1 < NT; ++kt) {                                                   \
        stage(cur ^ 1, kt + 1);                                                             \
        compute(cur);                                                                       \
        __syncthreads();                                                                    \
        cur ^= 1;                                                                           \
    }                                                                                       \
    compute(cur);                                                                           \
    const int rquad = (lane >> 4) * 4;                                                      \
    const int cl    = lane & 15;

template<int MODE>
__global__ __launch_bounds__(256, 3)
void gemm_nt(const ushort_t* __restrict__ A, int lda, long long aBatch,
             const ushort_t* __restrict__ B, int ldb, long long bBatch,
             void* __restrict__ Cv, int ldc, long long cBatch,
             const float* __restrict__ bias, float* __restrict__ rowsum,
             int K)
{
    int bx, by, bz;
    xcd_remap(bx, by, bz);
    const long long tM = (long long)by * BM;
    const long long tN = (long long)bx * BN;
    const int z = bz;
    const ushort_t* Ab = A + (long long)z * aBatch;
    const ushort_t* Bb = B + (long long)z * bBatch;

    GEMM_CORE(Ab, lda, Bb, ldb, K)

#pragma unroll
    for (int mi = 0; mi < 4; ++mi) {
        const long long r = tM + wr * 64 + mi * 16 + rquad;   // rows r..r+3
        if constexpr (MODE == M_PVN) {
            ushort_t* out = (ushort_t*)Cv + (long long)z * cBatch;
            float inv[4];
#pragma unroll
            for (int j = 0; j < 4; ++j)
                inv[j] = 1.0f / rowsum[(long long)z * 2048 + r + j];
#pragma unroll
            for (int ni = 0; ni < 4; ++ni) {
                f32x4 v = acc[mi][ni];
                const long long c = tN + wc * 64 + ni * 16 + cl;
#pragma unroll
                for (int j = 0; j < 4; ++j)
                    out[(r + j) * ldc + c] = f2bf(v[j] * inv[j]);
            }
        } else {  // M_OUT
            float* out = (float*)Cv;
#pragma unroll
            for (int ni = 0; ni < 4; ++ni) {
                f32x4 v = acc[mi][ni];
                const long long c = tN + wc * 64 + ni * 16 + cl;
                const float bc = bias[c];
#pragma unroll
                for (int j = 0; j < 4; ++j)
                    out[(r + j) * ldc + c] = v[j] + bc;
            }
        }
    }
}

// ---------------- launch ----------------
extern "C" void kernel_launch(void* const* d_in, const int* in_sizes, int n_in,
                              void* d_out, int out_size, void* d_ws, size_t ws_size,
                              hipStream_t stream) {
    (void)in_sizes; (void)n_in; (void)out_size; (void)ws_size;
    const float* q  = (const float*)d_in[0];
    const float* k  = (const float*)d_in[1];
    const float* v  = (const float*)d_in[2];
    const float* Wq = (const float*)d_in[3];
    const float* bq = (const float*)d_in[4];
    const float* Wk = (const float*)d_in[5];
    const float* bk = (const float*)d_in[6];
    const float* Wv = (const float*)d_in[7];
    const float* bv = (const float*)d_in[8];
    const float* Wp = (const float*)d_in[9];
    const float* bp = (const float*)d_in[10];
    float* out = (float*)d_out;

    // ---- workspace layout (round-9 proven, no live-overlay) ----
    char* ws = (char*)d_ws;
    ushort_t* vb  = (ushort_t*)(ws);                 // [0, 12.6M)
    ushort_t* qb  = (ushort_t*)(ws + 12582912LL);
    ushort_t* kb  = (ushort_t*)(ws + 25165824LL);
    ushort_t* P   = (ushort_t*)(ws + 12582912LL);    // overlays dead qb,kb + gap
    ushort_t* Wqb = (ushort_t*)(ws + 46137344LL);
    ushort_t* Wkb = (ushort_t*)(ws + 47316992LL);
    ushort_t* Wvb = (ushort_t*)(ws + 48496640LL);
    ushort_t* Wpb = (ushort_t*)(ws + 49676288LL);
    ushort_t* qp  = (ushort_t*)(ws + 50855936LL);    // [8192][768] bf16
    ushort_t* kp  = (ushort_t*)(ws + 63438848LL);    // [8192][768] bf16
    ushort_t* vpT = (ushort_t*)(ws + 76021760LL);    // [768][8192] bf16
    float* rowsum = (float*)(ws + 88604672LL);       // 8192 f32
    ushort_t* Ob  = qp;                              // O overlays dead qp

    const float scale = 1.0f / sqrtf(768.0f);

    // 1) cvt v ; 2) cvt all 4 weights ; 3) zero rowsum
    cvt_multi<<<dim3(6144, 1, 1), 256, 0, stream>>>(v, nullptr, nullptr, nullptr,
                                                    vb, nullptr, nullptr, nullptr, 1572864);
    cvt_multi<<<dim3(576, 1, 4), 256, 0, stream>>>(Wq, Wk, Wv, Wp, Wqb, Wkb, Wvb, Wpb, 147456);
    zero_f32<<<32, 256, 0, stream>>>(rowsum, 8192);

    // 4) fused: V-projection (96 tiles) + cvt of q,k (160 grid-stride blocks)
    vprojcvt<<<256, 512, 0, stream>>>(Wvb, vb, bv, vpT, q, k, qb, kb);

    // 5) Q,K projections (192 tiles, 1 round)
    projqk4<<<dim3(3, 32, 2), 512, 0, stream>>>(qb, kb, Wqb, Wkb, bq, bk, qp, kp);

    // 6) exp(QK^T) + rowsum (256 tiles, 1 round)
    sexp4<<<dim3(8, 8, 4), 512, 0, stream>>>(qp, kp, P, rowsum, scale);

    // 7) O = (P~ @ Vp^T) / rowsum ; 8) out = O @ Wp^T + bp
    gemm_nt<M_PVN><<<dim3(6, 16, 4), 256, 0, stream>>>(P, 2048, 4194304, vpT, 8192, 2048,
                                                       Ob, 768, 1572864, nullptr, rowsum, 2048);
    gemm_nt<M_OUT><<<dim3(6, 64, 1), 256, 0, stream>>>(Ob, 768, 0, Wpb, 768, 0, out, 768, 0, bp, nullptr, 768);
}

// Round 11
// 157.443 us; speedup vs baseline: 1.2591x; 1.0646x over previous
//
#include <hip/hip_runtime.h>
#include <hip/hip_bf16.h>
#include <math.h>

typedef __bf16 bf16x8 __attribute__((ext_vector_type(8)));
typedef float  f32x4  __attribute__((ext_vector_type(4)));
typedef float  f32x4v __attribute__((ext_vector_type(4)));
typedef unsigned short ushort_t;
typedef ushort_t u16x4 __attribute__((ext_vector_type(4)));
typedef ushort_t u16x8 __attribute__((ext_vector_type(8)));

__device__ __forceinline__ ushort_t f2bf(float f) {
    unsigned u = __builtin_bit_cast(unsigned, f);
    u += 0x7FFFu + ((u >> 16) & 1u);
    return (ushort_t)(u >> 16);
}
__device__ __forceinline__ float bf2f(ushort_t b) {
    return __builtin_bit_cast(float, (unsigned)b << 16);
}

// XCD-aware bijective remap (m157/m204). Requires total grid % 8 == 0.
__device__ __forceinline__ void xcd_remap(int& bx, int& by, int& bz) {
    const int gx = gridDim.x, gy = gridDim.y;
    const int nwg = gx * gy * gridDim.z;
    const int lin = (blockIdx.z * gy + blockIdx.y) * gx + blockIdx.x;
    const int chunk = nwg >> 3;
    int nid = (lin & 7) * chunk + (lin >> 3);
    bx = nid % gx; nid /= gx;
    by = nid % gy; bz = nid / gy;
}

// ---- one merged prep launch: cvt v (6144) + 4 weights (4x576) + zero (32) ----
__global__ __launch_bounds__(256)
void cvt_all(const float* __restrict__ v, const float* __restrict__ Wq,
             const float* __restrict__ Wk, const float* __restrict__ Wv,
             const float* __restrict__ Wp,
             ushort_t* __restrict__ vb, ushort_t* __restrict__ Wqb,
             ushort_t* __restrict__ Wkb, ushort_t* __restrict__ Wvb,
             ushort_t* __restrict__ Wpb, float* __restrict__ rowsum)
{
    const int b = blockIdx.x;
    if (b < 6144) {
        int i = b * 256 + threadIdx.x;
        f32x4v x = ((const f32x4v*)v)[i];
        u16x4 o = { f2bf(x.x), f2bf(x.y), f2bf(x.z), f2bf(x.w) };
        ((u16x4*)vb)[i] = o;
    } else if (b < 8448) {
        const int w = (b - 6144) / 576;
        const int bb = (b - 6144) % 576;
        const float* in  = w == 0 ? Wq : w == 1 ? Wk : w == 2 ? Wv : Wp;
        ushort_t*    out = w == 0 ? Wqb : w == 1 ? Wkb : w == 2 ? Wvb : Wpb;
        int i = bb * 256 + threadIdx.x;
        f32x4v x = ((const f32x4v*)in)[i];
        u16x4 o = { f2bf(x.x), f2bf(x.y), f2bf(x.z), f2bf(x.w) };
        ((u16x4*)out)[i] = o;
    } else {
        int i = (b - 8448) * 256 + threadIdx.x;
        rowsum[i] = 0.f;
    }
}

// ============================================================================
// 256x256 / BK=64 / 8-wave 2-PHASE core (round-6 proven: 36us/round, 0 bank
// conflicts, ~716 TF effective). Stage-next -> compute(64 MFMA/wave) ->
// __syncthreads per K-tile. LDS 128KB, T2 swizzle slot^(row&7) applied
// inverse-on-source (linear gload_lds dest, rule #21), T5 setprio.
// NOTE: kernels using this macro must not have params named
// tid/lane/wave/wm/wn/r16/kb/acc/lds/NT/rquad/cl.
// ============================================================================
#define GEMM256_CORE(Ab_, lda_, Bb_, ldb_, Kdim_)                                           \
    __shared__ __align__(16) ushort_t lds[2][2][2][128 * 64];                               \
    const int tid  = threadIdx.x;                                                           \
    const int lane = tid & 63;                                                              \
    const int wave = tid >> 6;                                                              \
    const int wm = wave >> 2, wn = wave & 3;                                                \
    const int r16 = lane & 15, kb = lane >> 4;                                              \
    f32x4 acc[8][4];                                                                        \
    _Pragma("unroll") for (int i = 0; i < 8; ++i)                                           \
        _Pragma("unroll") for (int j = 0; j < 4; ++j)                                       \
            acc[i][j] = (f32x4){0.f, 0.f, 0.f, 0.f};                                        \
    auto stage = [&](int kt) {                                                              \
        const int d  = kt & 1;                                                              \
        const int k0 = kt * 64;                                                             \
        _Pragma("unroll") for (int arr = 0; arr < 2; ++arr)                                 \
        _Pragma("unroll") for (int h = 0; h < 2; ++h)                                       \
        _Pragma("unroll") for (int l = 0; l < 2; ++l) {                                     \
            const int idx = l * 512 + tid;                                                  \
            const int row = idx >> 3, sl = idx & 7;                                         \
            const int ssrc = sl ^ (row & 7);                                                \
            const long long grow = h * 128 + row;                                           \
            const ushort_t* g = (arr == 0)                                                  \
                ? (Ab_) + (tM + grow) * (long long)(lda_) + k0 + ssrc * 8                   \
                : (Bb_) + (tN + grow) * (long long)(ldb_) + k0 + ssrc * 8;                  \
            ushort_t* lp = &lds[d][arr][h][idx * 8];                                        \
            __builtin_amdgcn_global_load_lds((const __attribute__((address_space(1))) void*)g, \
                                             (__attribute__((address_space(3))) void*)lp, 16, 0, 0); \
        }                                                                                   \
    };                                                                                      \
    auto compute = [&](int kt) {                                                            \
        const int d = kt & 1;                                                               \
        _Pragma("unroll") for (int kk = 0; kk < 2; ++kk) {                                  \
            bf16x8 bfr[4];                                                                  \
            _Pragma("unroll") for (int ni = 0; ni < 4; ++ni) {                              \
                const int row = (wn & 1) * 64 + ni * 16 + r16;                              \
                const int o16 = row * 8 + ((kk * 4 + kb) ^ (row & 7));                      \
                bfr[ni] = *(const bf16x8*)((const char*)&lds[d][1][wn >> 1][0] + o16 * 16); \
            }                                                                               \
            __builtin_amdgcn_s_setprio(1);                                                  \
            _Pragma("unroll") for (int mi = 0; mi < 8; ++mi) {                              \
                const int row = mi * 16 + r16;                                              \
                const int o16 = row * 8 + ((kk * 4 + kb) ^ (row & 7));                      \
                bf16x8 af = *(const bf16x8*)((const char*)&lds[d][0][wm][0] + o16 * 16);    \
                _Pragma("unroll") for (int ni = 0; ni < 4; ++ni)                            \
                    acc[mi][ni] = __builtin_amdgcn_mfma_f32_16x16x32_bf16(af, bfr[ni], acc[mi][ni], 0, 0, 0); \
            }                                                                               \
            __builtin_amdgcn_s_setprio(0);                                                  \
        }                                                                                   \
    };                                                                                      \
    const int NT = (Kdim_) / 64;                                                            \
    stage(0);                                                                               \
    __syncthreads();                                                                        \
    for (int t = 0; t < NT; ++t) {                                                          \
        if (t + 1 < NT) stage(t + 1);                                                       \
        compute(t);                                                                         \
        __syncthreads();                                                                    \
    }                                                                                       \
    const int rquad = (lane >> 4) * 4;                                                      \
    const int cl    = lane & 15;

// ------ fused: V-projection (blocks 0..95) + cvt of q,k (blocks 96..255) ----
// V-proj: vpT = Wv@vb^T + bv(row) -> [768][8192] (coalesced row-major store).
__global__ __launch_bounds__(512, 2)
void vprojcvt(const ushort_t* __restrict__ wv_, const ushort_t* __restrict__ vb_,
              const float* __restrict__ bv_, ushort_t* __restrict__ dvT_,
              const float* __restrict__ qf_, const float* __restrict__ kf_,
              ushort_t* __restrict__ qb_, ushort_t* __restrict__ kb_)
{
    if (blockIdx.x < 96) {
        const int id = blockIdx.x;
        const long long tM = (long long)(id % 3) * 256;    // feature rows (768)
        const long long tN = (long long)(id / 3) * 256;    // token cols (8192)
        const ushort_t* Ab = wv_;
        const ushort_t* Bb = vb_;

        GEMM256_CORE(Ab, 768, Bb, 768, 768)

#pragma unroll
        for (int mi = 0; mi < 8; ++mi) {
            const long long r = tM + wm * 128 + mi * 16 + rquad;
#pragma unroll
            for (int ni = 0; ni < 4; ++ni) {
                f32x4 v = acc[mi][ni];
                const long long c = tN + wn * 64 + ni * 16 + cl;
#pragma unroll
                for (int j = 0; j < 4; ++j)
                    dvT_[(r + j) * 8192 + c] = f2bf(v[j] + bv_[r + j]);
            }
        }
    } else {
        const long long stride = 160LL * 512;
        for (long long i = (long long)(blockIdx.x - 96) * 512 + threadIdx.x;
             i < 2LL * 1572864; i += stride) {
            const float* src; ushort_t* dst; long long off;
            if (i < 1572864) { src = qf_; dst = qb_; off = i; }
            else             { src = kf_; dst = kb_; off = i - 1572864; }
            f32x4v v4 = ((const f32x4v*)src)[off];
            u16x4 o = { f2bf(v4.x), f2bf(v4.y), f2bf(v4.z), f2bf(v4.w) };
            ((u16x4*)dst)[off] = o;
        }
    }
}

// ---------------- Q,K projections: grid (3,32,2) = 192 blocks, 1 round ------
__global__ __launch_bounds__(512, 2)
void projqk2(const ushort_t* __restrict__ qin, const ushort_t* __restrict__ kin,
             const ushort_t* __restrict__ Wqb, const ushort_t* __restrict__ Wkb,
             const float* __restrict__ bqv, const float* __restrict__ bkv,
             ushort_t* __restrict__ dq, ushort_t* __restrict__ dk)
{
    int bx, by, bz;
    xcd_remap(bx, by, bz);
    const int z = bz;
    const long long tM = (long long)by * 256;
    const long long tN = (long long)bx * 256;
    const ushort_t* Ab = z ? kin : qin;
    const ushort_t* Bb = z ? Wkb : Wqb;
    const float* bias  = z ? bkv : bqv;
    ushort_t* dst      = z ? dk : dq;

    GEMM256_CORE(Ab, 768, Bb, 768, 768)

#pragma unroll
    for (int mi = 0; mi < 8; ++mi) {
        const long long r = tM + wm * 128 + mi * 16 + rquad;
#pragma unroll
        for (int ni = 0; ni < 4; ++ni) {
            f32x4 v = acc[mi][ni];
            const long long c = tN + wn * 64 + ni * 16 + cl;
            const float bc = bias[c];
#pragma unroll
            for (int j = 0; j < 4; ++j)
                dst[(r + j) * 768 + c] = f2bf(v[j] + bc);
        }
    }
}

// ---- sexp: P~ = exp(scale*qp@kp^T) bf16 + rowsum atomics. (8,8,4) = 256 ----
__global__ __launch_bounds__(512, 2)
void sexp2(const ushort_t* __restrict__ qp, const ushort_t* __restrict__ kp,
           ushort_t* __restrict__ P, float* __restrict__ rowsum, float scale)
{
    int bx, by, bz;
    xcd_remap(bx, by, bz);
    const long long tM = (long long)by * 256;
    const long long tN = (long long)bx * 256;
    const int z = bz;
    const ushort_t* Ab = qp + (long long)z * 1572864;
    const ushort_t* Bb = kp + (long long)z * 1572864;

    GEMM256_CORE(Ab, 768, Bb, 768, 768)

    ushort_t* out = P + (long long)z * 4194304;
#pragma unroll
    for (int mi = 0; mi < 8; ++mi) {
        const long long r = tM + wm * 128 + mi * 16 + rquad;
        float rs[4] = {0.f, 0.f, 0.f, 0.f};
#pragma unroll
        for (int ni = 0; ni < 4; ++ni) {
            f32x4 v = acc[mi][ni];
            const long long c = tN + wn * 64 + ni * 16 + cl;
#pragma unroll
            for (int j = 0; j < 4; ++j) {
                float p = __expf(v[j] * scale);
                ushort_t pb = f2bf(p);
                out[(r + j) * 2048 + c] = pb;
                rs[j] += bf2f(pb);     // sum exactly what PV will read
            }
        }
#pragma unroll
        for (int j = 0; j < 4; ++j) {
            float s = rs[j];
            s += __shfl_xor(s, 1, 64);
            s += __shfl_xor(s, 2, 64);
            s += __shfl_xor(s, 4, 64);
            s += __shfl_xor(s, 8, 64);
            if (cl == 0) atomicAdd(&rowsum[(long long)z * 2048 + r + j], s);
        }
    }
}

// ============================================================================
// 128x128 / BK=32 core (round-3 proven config) for PVN and OUT.
// ============================================================================
#define M_PVN  1   // bf16 out * (1/rowsum[row]), batched
#define M_OUT  2   // fp32 out + bias

#define BM 128
#define BN 128
#define BK 32

#define GEMM_CORE(Ab_, lda_, Bb_, ldb_, Kdim_)                                              \
    __shared__ __align__(16) ushort_t lds[2][2][BM * BK];                                   \
    const int tid  = threadIdx.x;                                                           \
    const int lane = tid & 63;                                                              \
    const int wave = tid >> 6;                                                              \
    const int wr = wave >> 1, wc = wave & 1;                                                \
    f32x4 acc[4][4];                                                                        \
    _Pragma("unroll") for (int i = 0; i < 4; ++i)                                           \
        _Pragma("unroll") for (int j = 0; j < 4; ++j)                                       \
            acc[i][j] = (f32x4){0.f, 0.f, 0.f, 0.f};                                        \
    auto stage = [&](int buf, int kt) {                                                     \
        const int k0 = kt * BK;                                                             \
        _Pragma("unroll") for (int rnd = 0; rnd < 2; ++rnd) {                               \
            const int c    = tid + rnd * 256;                                               \
            const int row  = c >> 2;                                                        \
            const int slot = (c & 3) ^ (row & 3);                                           \
            const ushort_t* ga = (Ab_) + (tM + row) * (long long)(lda_) + k0 + slot * 8;    \
            const ushort_t* gb = (Bb_) + (tN + row) * (long long)(ldb_) + k0 + slot * 8;    \
            ushort_t* la = &lds[buf][0][(rnd * 256 + wave * 64) * 8];                       \
            ushort_t* lb = &lds[buf][1][(rnd * 256 + wave * 64) * 8];                       \
            __builtin_amdgcn_global_load_lds((const __attribute__((address_space(1))) void*)ga, \
                                             (__attribute__((address_space(3))) void*)la, 16, 0, 0); \
            __builtin_amdgcn_global_load_lds((const __attribute__((address_space(1))) void*)gb, \
                                             (__attribute__((address_space(3))) void*)lb, 16, 0, 0); \
        }                                                                                   \
    };                                                                                      \
    auto compute = [&](int buf) {                                                           \
        const int kb  = lane >> 4;                                                          \
        const int r16 = lane & 15;                                                          \
        bf16x8 af[4], bfr[4];                                                               \
        _Pragma("unroll") for (int mi = 0; mi < 4; ++mi) {                                  \
            const int row = wr * 64 + mi * 16 + r16;                                        \
            const int off = row * 64 + ((kb ^ (row & 3)) << 4);                             \
            af[mi] = *(const bf16x8*)((const char*)lds[buf][0] + off);                      \
        }                                                                                   \
        _Pragma("unroll") for (int ni = 0; ni < 4; ++ni) {                                  \
            const int row = wc * 64 + ni * 16 + r16;                                        \
            const int off = row * 64 + ((kb ^ (row & 3)) << 4);                             \
            bfr[ni] = *(const bf16x8*)((const char*)lds[buf][1] + off);                     \
        }                                                                                   \
        _Pragma("unroll") for (int mi = 0; mi < 4; ++mi)                                    \
            _Pragma("unroll") for (int ni = 0; ni < 4; ++ni)                                \
                acc[mi][ni] = __builtin_amdgcn_mfma_f32_16x16x32_bf16(af[mi], bfr[ni], acc[mi][ni], 0, 0, 0); \
    };                                                                                      \
    const int NT = (Kdim_) / BK;                                                            \
    stage(0, 0);                                                                            \
    __syncthreads();                                                                        \
    int cur = 0;                                                                            \
    for (int kt = 0; kt + 1 < NT; ++kt) {                                                   \
        stage(cur ^ 1, kt + 1);                                                             \
        compute(cur);                                                                       \
        __syncthreads();                                                                    \
        cur ^= 1;                                                                           \
    }                                                                                       \
    compute(cur);                                                                           \
    const int rquad = (lane >> 4) * 4;                                                      \
    const int cl    = lane & 15;

template<int MODE>
__global__ __launch_bounds__(256, 3)
void gemm_nt(const ushort_t* __restrict__ A, int lda, long long aBatch,
             const ushort_t* __restrict__ B, int ldb, long long bBatch,
             void* __restrict__ Cv, int ldc, long long cBatch,
             const float* __restrict__ bias, float* __restrict__ rowsum,
             int K)
{
    int bx, by, bz;
    xcd_remap(bx, by, bz);
    const long long tM = (long long)by * BM;
    const long long tN = (long long)bx * BN;
    const int z = bz;
    const ushort_t* Ab = A + (long long)z * aBatch;
    const ushort_t* Bb = B + (long long)z * bBatch;

    GEMM_CORE(Ab, lda, Bb, ldb, K)

#pragma unroll
    for (int mi = 0; mi < 4; ++mi) {
        const long long r = tM + wr * 64 + mi * 16 + rquad;   // rows r..r+3
        if constexpr (MODE == M_PVN) {
            ushort_t* out = (ushort_t*)Cv + (long long)z * cBatch;
            float inv[4];
#pragma unroll
            for (int j = 0; j < 4; ++j)
                inv[j] = 1.0f / rowsum[(long long)z * 2048 + r + j];
#pragma unroll
            for (int ni = 0; ni < 4; ++ni) {
                f32x4 v = acc[mi][ni];
                const long long c = tN + wc * 64 + ni * 16 + cl;
#pragma unroll
                for (int j = 0; j < 4; ++j)
                    out[(r + j) * ldc + c] = f2bf(v[j] * inv[j]);
            }
        } else {  // M_OUT
            float* out = (float*)Cv;
#pragma unroll
            for (int ni = 0; ni < 4; ++ni) {
                f32x4 v = acc[mi][ni];
                const long long c = tN + wc * 64 + ni * 16 + cl;
                const float bc = bias[c];
#pragma unroll
                for (int j = 0; j < 4; ++j)
                    out[(r + j) * ldc + c] = v[j] + bc;
            }
        }
    }
}

// ---------------- launch ----------------
extern "C" void kernel_launch(void* const* d_in, const int* in_sizes, int n_in,
                              void* d_out, int out_size, void* d_ws, size_t ws_size,
                              hipStream_t stream) {
    (void)in_sizes; (void)n_in; (void)out_size; (void)ws_size;
    const float* q  = (const float*)d_in[0];
    const float* k  = (const float*)d_in[1];
    const float* v  = (const float*)d_in[2];
    const float* Wq = (const float*)d_in[3];
    const float* bq = (const float*)d_in[4];
    const float* Wk = (const float*)d_in[5];
    const float* bk = (const float*)d_in[6];
    const float* Wv = (const float*)d_in[7];
    const float* bv = (const float*)d_in[8];
    const float* Wp = (const float*)d_in[9];
    const float* bp = (const float*)d_in[10];
    float* out = (float*)d_out;

    // ---- workspace layout (round-9 proven, no live-overlay) ----
    char* ws = (char*)d_ws;
    ushort_t* vb  = (ushort_t*)(ws);                 // [0, 12.6M)
    ushort_t* qb  = (ushort_t*)(ws + 12582912LL);
    ushort_t* kb  = (ushort_t*)(ws + 25165824LL);
    ushort_t* P   = (ushort_t*)(ws + 12582912LL);    // overlays dead qb,kb + gap
    ushort_t* Wqb = (ushort_t*)(ws + 46137344LL);
    ushort_t* Wkb = (ushort_t*)(ws + 47316992LL);
    ushort_t* Wvb = (ushort_t*)(ws + 48496640LL);
    ushort_t* Wpb = (ushort_t*)(ws + 49676288LL);
    ushort_t* qp  = (ushort_t*)(ws + 50855936LL);    // [8192][768] bf16
    ushort_t* kp  = (ushort_t*)(ws + 63438848LL);    // [8192][768] bf16
    ushort_t* vpT = (ushort_t*)(ws + 76021760LL);    // [768][8192] bf16
    float* rowsum = (float*)(ws + 88604672LL);       // 8192 f32
    ushort_t* Ob  = qp;                              // O overlays dead qp

    const float scale = 1.0f / sqrtf(768.0f);

    // 1) merged prep: cvt v, cvt 4 weights, zero rowsum
    cvt_all<<<8480, 256, 0, stream>>>(v, Wq, Wk, Wv, Wp, vb, Wqb, Wkb, Wvb, Wpb, rowsum);

    // 2) fused: V-projection (96 tiles, 2ph core) + cvt of q,k (160 blocks)
    vprojcvt<<<256, 512, 0, stream>>>(Wvb, vb, bv, vpT, q, k, qb, kb);

    // 3) Q,K projections (192 tiles, 1 round)
    projqk2<<<dim3(3, 32, 2), 512, 0, stream>>>(qb, kb, Wqb, Wkb, bq, bk, qp, kp);

    // 4) exp(QK^T) + rowsum (256 tiles, 1 round)
    sexp2<<<dim3(8, 8, 4), 512, 0, stream>>>(qp, kp, P, rowsum, scale);

    // 5) O = (P~ @ Vp^T) / rowsum ; 6) out = O @ Wp^T + bp
    gemm_nt<M_PVN><<<dim3(6, 16, 4), 256, 0, stream>>>(P, 2048, 4194304, vpT, 8192, 2048,
                                                       Ob, 768, 1572864, nullptr, rowsum, 2048);
    gemm_nt<M_OUT><<<dim3(6, 64, 1), 256, 0, stream>>>(Ob, 768, 0, Wpb, 768, 0, out, 768, 0, bp, nullptr, 768);
}

// Round 12
// 153.148 us; speedup vs baseline: 1.2944x; 1.0280x over previous
//
#include <hip/hip_runtime.h>
#include <hip/hip_bf16.h>
#include <math.h>

typedef __bf16 bf16x8 __attribute__((ext_vector_type(8)));
typedef float  f32x4  __attribute__((ext_vector_type(4)));
typedef float  f32x4v __attribute__((ext_vector_type(4)));
typedef unsigned short ushort_t;
typedef ushort_t u16x4 __attribute__((ext_vector_type(4)));
typedef ushort_t u16x8 __attribute__((ext_vector_type(8)));

__device__ __forceinline__ ushort_t f2bf(float f) {
    unsigned u = __builtin_bit_cast(unsigned, f);
    u += 0x7FFFu + ((u >> 16) & 1u);
    return (ushort_t)(u >> 16);
}

// XCD-aware bijective remap (m157/m204). Requires total grid % 8 == 0.
__device__ __forceinline__ void xcd_remap(int& bx, int& by, int& bz) {
    const int gx = gridDim.x, gy = gridDim.y;
    const int nwg = gx * gy * gridDim.z;
    const int lin = (blockIdx.z * gy + blockIdx.y) * gx + blockIdx.x;
    const int chunk = nwg >> 3;
    int nid = (lin & 7) * chunk + (lin >> 3);
    bx = nid % gx; nid /= gx;
    by = nid % gy; bz = nid / gy;
}

// ---- merged prep launch: cvt v (6144 blocks) + 4 weights (4x576) ----
__global__ __launch_bounds__(256)
void cvt_all(const float* __restrict__ v, const float* __restrict__ Wq,
             const float* __restrict__ Wk, const float* __restrict__ Wv,
             const float* __restrict__ Wp,
             ushort_t* __restrict__ vb, ushort_t* __restrict__ Wqb,
             ushort_t* __restrict__ Wkb, ushort_t* __restrict__ Wvb,
             ushort_t* __restrict__ Wpb)
{
    const int b = blockIdx.x;
    if (b < 6144) {
        int i = b * 256 + threadIdx.x;
        f32x4v x = ((const f32x4v*)v)[i];
        u16x4 o = { f2bf(x.x), f2bf(x.y), f2bf(x.z), f2bf(x.w) };
        ((u16x4*)vb)[i] = o;
    } else {
        const int w = (b - 6144) / 576;
        const int bb = (b - 6144) % 576;
        const float* in  = w == 0 ? Wq : w == 1 ? Wk : w == 2 ? Wv : Wp;
        ushort_t*    out = w == 0 ? Wqb : w == 1 ? Wkb : w == 2 ? Wvb : Wpb;
        int i = bb * 256 + threadIdx.x;
        f32x4v x = ((const f32x4v*)in)[i];
        u16x4 o = { f2bf(x.x), f2bf(x.y), f2bf(x.z), f2bf(x.w) };
        ((u16x4*)out)[i] = o;
    }
}

// ============================================================================
// 256x256 / BK=64 / 8-wave 2-PHASE core (round-6 proven). T2 swizzle applied
// inverse-on-source (linear gload_lds dest, rule #21), T5 setprio.
// ============================================================================
#define GEMM256_CORE(Ab_, lda_, Bb_, ldb_, Kdim_)                                           \
    __shared__ __align__(16) ushort_t lds[2][2][2][128 * 64];                               \
    const int tid  = threadIdx.x;                                                           \
    const int lane = tid & 63;                                                              \
    const int wave = tid >> 6;                                                              \
    const int wm = wave >> 2, wn = wave & 3;                                                \
    const int r16 = lane & 15, kb = lane >> 4;                                              \
    f32x4 acc[8][4];                                                                        \
    _Pragma("unroll") for (int i = 0; i < 8; ++i)                                           \
        _Pragma("unroll") for (int j = 0; j < 4; ++j)                                       \
            acc[i][j] = (f32x4){0.f, 0.f, 0.f, 0.f};                                        \
    auto stage = [&](int kt) {                                                              \
        const int d  = kt & 1;                                                              \
        const int k0 = kt * 64;                                                             \
        _Pragma("unroll") for (int arr = 0; arr < 2; ++arr)                                 \
        _Pragma("unroll") for (int h = 0; h < 2; ++h)                                       \
        _Pragma("unroll") for (int l = 0; l < 2; ++l) {                                     \
            const int idx = l * 512 + tid;                                                  \
            const int row = idx >> 3, sl = idx & 7;                                         \
            const int ssrc = sl ^ (row & 7);                                                \
            const long long grow = h * 128 + row;                                           \
            const ushort_t* g = (arr == 0)                                                  \
                ? (Ab_) + (tM + grow) * (long long)(lda_) + k0 + ssrc * 8                   \
                : (Bb_) + (tN + grow) * (long long)(ldb_) + k0 + ssrc * 8;                  \
            ushort_t* lp = &lds[d][arr][h][idx * 8];                                        \
            __builtin_amdgcn_global_load_lds((const __attribute__((address_space(1))) void*)g, \
                                             (__attribute__((address_space(3))) void*)lp, 16, 0, 0); \
        }                                                                                   \
    };                                                                                      \
    auto compute = [&](int kt) {                                                            \
        const int d = kt & 1;                                                               \
        _Pragma("unroll") for (int kk = 0; kk < 2; ++kk) {                                  \
            bf16x8 bfr[4];                                                                  \
            _Pragma("unroll") for (int ni = 0; ni < 4; ++ni) {                              \
                const int row = (wn & 1) * 64 + ni * 16 + r16;                              \
                const int o16 = row * 8 + ((kk * 4 + kb) ^ (row & 7));                      \
                bfr[ni] = *(const bf16x8*)((const char*)&lds[d][1][wn >> 1][0] + o16 * 16); \
            }                                                                               \
            __builtin_amdgcn_s_setprio(1);                                                  \
            _Pragma("unroll") for (int mi = 0; mi < 8; ++mi) {                              \
                const int row = mi * 16 + r16;                                              \
                const int o16 = row * 8 + ((kk * 4 + kb) ^ (row & 7));                      \
                bf16x8 af = *(const bf16x8*)((const char*)&lds[d][0][wm][0] + o16 * 16);    \
                _Pragma("unroll") for (int ni = 0; ni < 4; ++ni)                            \
                    acc[mi][ni] = __builtin_amdgcn_mfma_f32_16x16x32_bf16(af, bfr[ni], acc[mi][ni], 0, 0, 0); \
            }                                                                               \
            __builtin_amdgcn_s_setprio(0);                                                  \
        }                                                                                   \
    };                                                                                      \
    const int NT = (Kdim_) / 64;                                                            \
    stage(0);                                                                               \
    __syncthreads();                                                                        \
    for (int t = 0; t < NT; ++t) {                                                          \
        if (t + 1 < NT) stage(t + 1);                                                       \
        compute(t);                                                                         \
        __syncthreads();                                                                    \
    }                                                                                       \
    const int rquad = (lane >> 4) * 4;                                                      \
    const int cl    = lane & 15;

// ------ fused: V-projection (blocks 0..95) + cvt of q,k (blocks 96..255) ----
__global__ __launch_bounds__(512, 2)
void vprojcvt(const ushort_t* __restrict__ wv_, const ushort_t* __restrict__ vb_,
              const float* __restrict__ bv_, ushort_t* __restrict__ dvT_,
              const float* __restrict__ qf_, const float* __restrict__ kf_,
              ushort_t* __restrict__ qb_, ushort_t* __restrict__ kb_)
{
    if (blockIdx.x < 96) {
        const int id = blockIdx.x;
        const long long tM = (long long)(id % 3) * 256;    // feature rows (768)
        const long long tN = (long long)(id / 3) * 256;    // token cols (8192)
        const ushort_t* Ab = wv_;
        const ushort_t* Bb = vb_;

        GEMM256_CORE(Ab, 768, Bb, 768, 768)

#pragma unroll
        for (int mi = 0; mi < 8; ++mi) {
            const long long r = tM + wm * 128 + mi * 16 + rquad;
#pragma unroll
            for (int ni = 0; ni < 4; ++ni) {
                f32x4 v = acc[mi][ni];
                const long long c = tN + wn * 64 + ni * 16 + cl;
#pragma unroll
                for (int j = 0; j < 4; ++j)
                    dvT_[(r + j) * 8192 + c] = f2bf(v[j] + bv_[r + j]);
            }
        }
    } else {
        const long long stride = 160LL * 512;
        for (long long i = (long long)(blockIdx.x - 96) * 512 + threadIdx.x;
             i < 2LL * 1572864; i += stride) {
            const float* src; ushort_t* dst; long long off;
            if (i < 1572864) { src = qf_; dst = qb_; off = i; }
            else             { src = kf_; dst = kb_; off = i - 1572864; }
            f32x4v v4 = ((const f32x4v*)src)[off];
            u16x4 o = { f2bf(v4.x), f2bf(v4.y), f2bf(v4.z), f2bf(v4.w) };
            ((u16x4*)dst)[off] = o;
        }
    }
}

// ---------------- Q,K projections: grid (3,32,2) = 192 blocks, 1 round ------
__global__ __launch_bounds__(512, 2)
void projqk2(const ushort_t* __restrict__ qin, const ushort_t* __restrict__ kin,
             const ushort_t* __restrict__ Wqb, const ushort_t* __restrict__ Wkb,
             const float* __restrict__ bqv, const float* __restrict__ bkv,
             ushort_t* __restrict__ dq, ushort_t* __restrict__ dk)
{
    int bx, by, bz;
    xcd_remap(bx, by, bz);
    const int z = bz;
    const long long tM = (long long)by * 256;
    const long long tN = (long long)bx * 256;
    const ushort_t* Ab = z ? kin : qin;
    const ushort_t* Bb = z ? Wkb : Wqb;
    const float* bias  = z ? bkv : bqv;
    ushort_t* dst      = z ? dk : dq;

    GEMM256_CORE(Ab, 768, Bb, 768, 768)

#pragma unroll
    for (int mi = 0; mi < 8; ++mi) {
        const long long r = tM + wm * 128 + mi * 16 + rquad;
#pragma unroll
        for (int ni = 0; ni < 4; ++ni) {
            f32x4 v = acc[mi][ni];
            const long long c = tN + wn * 64 + ni * 16 + cl;
            const float bc = bias[c];
#pragma unroll
            for (int j = 0; j < 4; ++j)
                dst[(r + j) * 768 + c] = f2bf(v[j] + bc);
        }
    }
}

// ---- sexp: P~ = exp(scale*qp@kp^T) bf16. (8,8,4) = 256 blocks. No rowsum. ----
__global__ __launch_bounds__(512, 2)
void sexp2(const ushort_t* __restrict__ qp, const ushort_t* __restrict__ kp,
           ushort_t* __restrict__ P, float scale)
{
    int bx, by, bz;
    xcd_remap(bx, by, bz);
    const long long tM = (long long)by * 256;
    const long long tN = (long long)bx * 256;
    const int z = bz;
    const ushort_t* Ab = qp + (long long)z * 1572864;
    const ushort_t* Bb = kp + (long long)z * 1572864;

    GEMM256_CORE(Ab, 768, Bb, 768, 768)

    ushort_t* out = P + (long long)z * 4194304;
#pragma unroll
    for (int mi = 0; mi < 8; ++mi) {
        const long long r = tM + wm * 128 + mi * 16 + rquad;
#pragma unroll
        for (int ni = 0; ni < 4; ++ni) {
            f32x4 v = acc[mi][ni];
            const long long c = tN + wn * 64 + ni * 16 + cl;
#pragma unroll
            for (int j = 0; j < 4; ++j)
                out[(r + j) * 2048 + c] = f2bf(__expf(v[j] * scale));
        }
    }
}

// ============================================================================
// PVN: O = (P @ Vp^T) / rowsum, 128x128/BK=32 core + ones-MFMA rowsum.
// rs4[mi] = mfma(af[mi], ones) accumulates row-sums of P in EXACTLY the
// accumulator C-layout (reg j <-> row rquad+j), so normalization needs no
// shuffles/atomics. Sums the same bf16 P values the PV MFMAs consume.
// ============================================================================
__global__ __launch_bounds__(256, 3)
void pvn_rs(const ushort_t* __restrict__ Pg, const ushort_t* __restrict__ vpT,
            ushort_t* __restrict__ Og)
{
    int bx, by, bz;
    xcd_remap(bx, by, bz);
    const long long tM = (long long)by * 128;
    const long long tN = (long long)bx * 128;
    const int z = bz;
    const ushort_t* Ab = Pg + (long long)z * 4194304;   // P: [2048][2048] bf16
    const ushort_t* Bb = vpT + (long long)z * 2048;     // vpT: [768][8192], batch = col offset

    __shared__ __align__(16) ushort_t lds[2][2][128 * 32];
    const int tid  = threadIdx.x;
    const int lane = tid & 63;
    const int wave = tid >> 6;
    const int wr = wave >> 1, wc = wave & 1;

    const u16x8 oneb = {0x3F80,0x3F80,0x3F80,0x3F80,0x3F80,0x3F80,0x3F80,0x3F80};
    const bf16x8 ones = __builtin_bit_cast(bf16x8, oneb);

    f32x4 acc[4][4];
    f32x4 rs4[4];
#pragma unroll
    for (int i = 0; i < 4; ++i) {
        rs4[i] = (f32x4){0.f, 0.f, 0.f, 0.f};
#pragma unroll
        for (int j = 0; j < 4; ++j)
            acc[i][j] = (f32x4){0.f, 0.f, 0.f, 0.f};
    }

    auto stage = [&](int buf, int kt) {
        const int k0 = kt * 32;
#pragma unroll
        for (int rnd = 0; rnd < 2; ++rnd) {
            const int c    = tid + rnd * 256;
            const int row  = c >> 2;
            const int slot = (c & 3) ^ (row & 3);
            const ushort_t* ga = Ab + (tM + row) * 2048LL + k0 + slot * 8;
            const ushort_t* gb = Bb + (tN + row) * 8192LL + k0 + slot * 8;
            ushort_t* la = &lds[buf][0][(rnd * 256 + wave * 64) * 8];
            ushort_t* lb = &lds[buf][1][(rnd * 256 + wave * 64) * 8];
            __builtin_amdgcn_global_load_lds((const __attribute__((address_space(1))) void*)ga,
                                             (__attribute__((address_space(3))) void*)la, 16, 0, 0);
            __builtin_amdgcn_global_load_lds((const __attribute__((address_space(1))) void*)gb,
                                             (__attribute__((address_space(3))) void*)lb, 16, 0, 0);
        }
    };
    auto compute = [&](int buf) {
        const int kb  = lane >> 4;
        const int r16 = lane & 15;
        bf16x8 af[4], bfr[4];
#pragma unroll
        for (int mi = 0; mi < 4; ++mi) {
            const int row = wr * 64 + mi * 16 + r16;
            const int off = row * 64 + ((kb ^ (row & 3)) << 4);
            af[mi] = *(const bf16x8*)((const char*)lds[buf][0] + off);
        }
#pragma unroll
        for (int ni = 0; ni < 4; ++ni) {
            const int row = wc * 64 + ni * 16 + r16;
            const int off = row * 64 + ((kb ^ (row & 3)) << 4);
            bfr[ni] = *(const bf16x8*)((const char*)lds[buf][1] + off);
        }
#pragma unroll
        for (int mi = 0; mi < 4; ++mi) {
#pragma unroll
            for (int ni = 0; ni < 4; ++ni)
                acc[mi][ni] = __builtin_amdgcn_mfma_f32_16x16x32_bf16(af[mi], bfr[ni], acc[mi][ni], 0, 0, 0);
            rs4[mi] = __builtin_amdgcn_mfma_f32_16x16x32_bf16(af[mi], ones, rs4[mi], 0, 0, 0);
        }
    };

    stage(0, 0);
    __syncthreads();
    int cur = 0;
    for (int kt = 0; kt + 1 < 64; ++kt) {
        stage(cur ^ 1, kt + 1);
        compute(cur);
        __syncthreads();
        cur ^= 1;
    }
    compute(cur);

    const int rquad = (lane >> 4) * 4;
    const int cl    = lane & 15;
    ushort_t* out = Og + (long long)z * 1572864;
#pragma unroll
    for (int mi = 0; mi < 4; ++mi) {
        const long long r = tM + wr * 64 + mi * 16 + rquad;
        float inv[4];
#pragma unroll
        for (int j = 0; j < 4; ++j)
            inv[j] = 1.0f / rs4[mi][j];
#pragma unroll
        for (int ni = 0; ni < 4; ++ni) {
            f32x4 v = acc[mi][ni];
            const long long c = tN + wc * 64 + ni * 16 + cl;
#pragma unroll
            for (int j = 0; j < 4; ++j)
                out[(r + j) * 768 + c] = f2bf(v[j] * inv[j]);
        }
    }
}

// ---------------- OUT: fp32 = O @ Wp^T + bp, 128x128/BK=32 core -------------
__global__ __launch_bounds__(256, 3)
void gemm_out(const ushort_t* __restrict__ A, const ushort_t* __restrict__ B,
              float* __restrict__ Cg, const float* __restrict__ bias)
{
    int bx, by, bz;
    xcd_remap(bx, by, bz);
    const long long tM = (long long)by * 128;
    const long long tN = (long long)bx * 128;
    const ushort_t* Ab = A;
    const ushort_t* Bb = B;

    __shared__ __align__(16) ushort_t lds[2][2][128 * 32];
    const int tid  = threadIdx.x;
    const int lane = tid & 63;
    const int wave = tid >> 6;
    const int wr = wave >> 1, wc = wave & 1;
    f32x4 acc[4][4];
#pragma unroll
    for (int i = 0; i < 4; ++i)
#pragma unroll
        for (int j = 0; j < 4; ++j)
            acc[i][j] = (f32x4){0.f, 0.f, 0.f, 0.f};

    auto stage = [&](int buf, int kt) {
        const int k0 = kt * 32;
#pragma unroll
        for (int rnd = 0; rnd < 2; ++rnd) {
            const int c    = tid + rnd * 256;
            const int row  = c >> 2;
            const int slot = (c & 3) ^ (row & 3);
            const ushort_t* ga = Ab + (tM + row) * 768LL + k0 + slot * 8;
            const ushort_t* gb = Bb + (tN + row) * 768LL + k0 + slot * 8;
            ushort_t* la = &lds[buf][0][(rnd * 256 + wave * 64) * 8];
            ushort_t* lb = &lds[buf][1][(rnd * 256 + wave * 64) * 8];
            __builtin_amdgcn_global_load_lds((const __attribute__((address_space(1))) void*)ga,
                                             (__attribute__((address_space(3))) void*)la, 16, 0, 0);
            __builtin_amdgcn_global_load_lds((const __attribute__((address_space(1))) void*)gb,
                                             (__attribute__((address_space(3))) void*)lb, 16, 0, 0);
        }
    };
    auto compute = [&](int buf) {
        const int kb  = lane >> 4;
        const int r16 = lane & 15;
        bf16x8 af[4], bfr[4];
#pragma unroll
        for (int mi = 0; mi < 4; ++mi) {
            const int row = wr * 64 + mi * 16 + r16;
            const int off = row * 64 + ((kb ^ (row & 3)) << 4);
            af[mi] = *(const bf16x8*)((const char*)lds[buf][0] + off);
        }
#pragma unroll
        for (int ni = 0; ni < 4; ++ni) {
            const int row = wc * 64 + ni * 16 + r16;
            const int off = row * 64 + ((kb ^ (row & 3)) << 4);
            bfr[ni] = *(const bf16x8*)((const char*)lds[buf][1] + off);
        }
#pragma unroll
        for (int mi = 0; mi < 4; ++mi)
#pragma unroll
            for (int ni = 0; ni < 4; ++ni)
                acc[mi][ni] = __builtin_amdgcn_mfma_f32_16x16x32_bf16(af[mi], bfr[ni], acc[mi][ni], 0, 0, 0);
    };

    stage(0, 0);
    __syncthreads();
    int cur = 0;
    for (int kt = 0; kt + 1 < 24; ++kt) {
        stage(cur ^ 1, kt + 1);
        compute(cur);
        __syncthreads();
        cur ^= 1;
    }
    compute(cur);

    const int rquad = (lane >> 4) * 4;
    const int cl    = lane & 15;
#pragma unroll
    for (int mi = 0; mi < 4; ++mi) {
        const long long r = tM + wr * 64 + mi * 16 + rquad;
#pragma unroll
        for (int ni = 0; ni < 4; ++ni) {
            f32x4 v = acc[mi][ni];
            const long long c = tN + wc * 64 + ni * 16 + cl;
            const float bc = bias[c];
#pragma unroll
            for (int j = 0; j < 4; ++j)
                Cg[(r + j) * 768 + c] = v[j] + bc;
        }
    }
}

// ---------------- launch ----------------
extern "C" void kernel_launch(void* const* d_in, const int* in_sizes, int n_in,
                              void* d_out, int out_size, void* d_ws, size_t ws_size,
                              hipStream_t stream) {
    (void)in_sizes; (void)n_in; (void)out_size; (void)ws_size;
    const float* q  = (const float*)d_in[0];
    const float* k  = (const float*)d_in[1];
    const float* v  = (const float*)d_in[2];
    const float* Wq = (const float*)d_in[3];
    const float* bq = (const float*)d_in[4];
    const float* Wk = (const float*)d_in[5];
    const float* bk = (const float*)d_in[6];
    const float* Wv = (const float*)d_in[7];
    const float* bv = (const float*)d_in[8];
    const float* Wp = (const float*)d_in[9];
    const float* bp = (const float*)d_in[10];
    float* out = (float*)d_out;

    // ---- workspace layout (round-9 proven, no live-overlay) ----
    char* ws = (char*)d_ws;
    ushort_t* vb  = (ushort_t*)(ws);                 // [0, 12.6M)
    ushort_t* qb  = (ushort_t*)(ws + 12582912LL);
    ushort_t* kb  = (ushort_t*)(ws + 25165824LL);
    ushort_t* P   = (ushort_t*)(ws + 12582912LL);    // overlays dead qb,kb + gap
    ushort_t* Wqb = (ushort_t*)(ws + 46137344LL);
    ushort_t* Wkb = (ushort_t*)(ws + 47316992LL);
    ushort_t* Wvb = (ushort_t*)(ws + 48496640LL);
    ushort_t* Wpb = (ushort_t*)(ws + 49676288LL);
    ushort_t* qp  = (ushort_t*)(ws + 50855936LL);    // [8192][768] bf16
    ushort_t* kp  = (ushort_t*)(ws + 63438848LL);    // [8192][768] bf16
    ushort_t* vpT = (ushort_t*)(ws + 76021760LL);    // [768][8192] bf16
    ushort_t* Ob  = qp;                              // O overlays dead qp

    const float scale = 1.0f / sqrtf(768.0f);

    // 1) merged prep: cvt v + 4 weights
    cvt_all<<<8448, 256, 0, stream>>>(v, Wq, Wk, Wv, Wp, vb, Wqb, Wkb, Wvb, Wpb);

    // 2) fused: V-projection (96 tiles) + cvt of q,k (160 blocks)
    vprojcvt<<<256, 512, 0, stream>>>(Wvb, vb, bv, vpT, q, k, qb, kb);

    // 3) Q,K projections (192 tiles, 1 round)
    projqk2<<<dim3(3, 32, 2), 512, 0, stream>>>(qb, kb, Wqb, Wkb, bq, bk, qp, kp);

    // 4) P~ = exp(scale * QK^T)  (256 tiles, 1 round; no rowsum side-work)
    sexp2<<<dim3(8, 8, 4), 512, 0, stream>>>(qp, kp, P, scale);

    // 5) O = (P~ @ Vp^T) / rowsum   (rowsum via ones-MFMA inside)
    pvn_rs<<<dim3(6, 16, 4), 256, 0, stream>>>(P, vpT, Ob);

    // 6) out = O @ Wp^T + bp
    gemm_out<<<dim3(6, 64, 1), 256, 0, stream>>>(Ob, Wpb, out, bp);
}

// Round 13
// 147.675 us; speedup vs baseline: 1.3424x; 1.0371x over previous
//
#include <hip/hip_runtime.h>
#include <hip/hip_bf16.h>
#include <math.h>

typedef __bf16 bf16x8 __attribute__((ext_vector_type(8)));
typedef float  f32x4  __attribute__((ext_vector_type(4)));
typedef float  f32x4v __attribute__((ext_vector_type(4)));
typedef unsigned short ushort_t;
typedef ushort_t u16x4 __attribute__((ext_vector_type(4)));
typedef ushort_t u16x8 __attribute__((ext_vector_type(8)));

__device__ __forceinline__ ushort_t f2bf(float f) {
    unsigned u = __builtin_bit_cast(unsigned, f);
    u += 0x7FFFu + ((u >> 16) & 1u);
    return (ushort_t)(u >> 16);
}

// XCD-aware bijective remap (m157/m204). Requires total grid % 8 == 0.
__device__ __forceinline__ void xcd_remap(int& bx, int& by, int& bz) {
    const int gx = gridDim.x, gy = gridDim.y;
    const int nwg = gx * gy * gridDim.z;
    const int lin = (blockIdx.z * gy + blockIdx.y) * gx + blockIdx.x;
    const int chunk = nwg >> 3;
    int nid = (lin & 7) * chunk + (lin >> 3);
    bx = nid % gx; nid /= gx;
    by = nid % gy; bz = nid / gy;
}

// ---- merged prep launch: cvt v (6144 blocks) + 4 weights (4x576) ----
__global__ __launch_bounds__(256)
void cvt_all(const float* __restrict__ v, const float* __restrict__ Wq,
             const float* __restrict__ Wk, const float* __restrict__ Wv,
             const float* __restrict__ Wp,
             ushort_t* __restrict__ vb, ushort_t* __restrict__ Wqb,
             ushort_t* __restrict__ Wkb, ushort_t* __restrict__ Wvb,
             ushort_t* __restrict__ Wpb)
{
    const int b = blockIdx.x;
    if (b < 6144) {
        int i = b * 256 + threadIdx.x;
        f32x4v x = ((const f32x4v*)v)[i];
        u16x4 o = { f2bf(x.x), f2bf(x.y), f2bf(x.z), f2bf(x.w) };
        ((u16x4*)vb)[i] = o;
    } else {
        const int w = (b - 6144) / 576;
        const int bb = (b - 6144) % 576;
        const float* in  = w == 0 ? Wq : w == 1 ? Wk : w == 2 ? Wv : Wp;
        ushort_t*    out = w == 0 ? Wqb : w == 1 ? Wkb : w == 2 ? Wvb : Wpb;
        int i = bb * 256 + threadIdx.x;
        f32x4v x = ((const f32x4v*)in)[i];
        u16x4 o = { f2bf(x.x), f2bf(x.y), f2bf(x.z), f2bf(x.w) };
        ((u16x4*)out)[i] = o;
    }
}

// ============================================================================
// 256x256 / BK=64 / 8-wave 2-PHASE core (round-6 proven). T2 swizzle applied
// inverse-on-source (linear gload_lds dest, rule #21), T5 setprio.
// ============================================================================
#define GEMM256_CORE(Ab_, lda_, Bb_, ldb_, Kdim_)                                           \
    __shared__ __align__(16) ushort_t lds[2][2][2][128 * 64];                               \
    const int tid  = threadIdx.x;                                                           \
    const int lane = tid & 63;                                                              \
    const int wave = tid >> 6;                                                              \
    const int wm = wave >> 2, wn = wave & 3;                                                \
    const int r16 = lane & 15, kb = lane >> 4;                                              \
    f32x4 acc[8][4];                                                                        \
    _Pragma("unroll") for (int i = 0; i < 8; ++i)                                           \
        _Pragma("unroll") for (int j = 0; j < 4; ++j)                                       \
            acc[i][j] = (f32x4){0.f, 0.f, 0.f, 0.f};                                        \
    auto stage = [&](int kt) {                                                              \
        const int d  = kt & 1;                                                              \
        const int k0 = kt * 64;                                                             \
        _Pragma("unroll") for (int arr = 0; arr < 2; ++arr)                                 \
        _Pragma("unroll") for (int h = 0; h < 2; ++h)                                       \
        _Pragma("unroll") for (int l = 0; l < 2; ++l) {                                     \
            const int idx = l * 512 + tid;                                                  \
            const int row = idx >> 3, sl = idx & 7;                                         \
            const int ssrc = sl ^ (row & 7);                                                \
            const long long grow = h * 128 + row;                                           \
            const ushort_t* g = (arr == 0)                                                  \
                ? (Ab_) + (tM + grow) * (long long)(lda_) + k0 + ssrc * 8                   \
                : (Bb_) + (tN + grow) * (long long)(ldb_) + k0 + ssrc * 8;                  \
            ushort_t* lp = &lds[d][arr][h][idx * 8];                                        \
            __builtin_amdgcn_global_load_lds((const __attribute__((address_space(1))) void*)g, \
                                             (__attribute__((address_space(3))) void*)lp, 16, 0, 0); \
        }                                                                                   \
    };                                                                                      \
    auto compute = [&](int kt) {                                                            \
        const int d = kt & 1;                                                               \
        _Pragma("unroll") for (int kk = 0; kk < 2; ++kk) {                                  \
            bf16x8 bfr[4];                                                                  \
            _Pragma("unroll") for (int ni = 0; ni < 4; ++ni) {                              \
                const int row = (wn & 1) * 64 + ni * 16 + r16;                              \
                const int o16 = row * 8 + ((kk * 4 + kb) ^ (row & 7));                      \
                bfr[ni] = *(const bf16x8*)((const char*)&lds[d][1][wn >> 1][0] + o16 * 16); \
            }                                                                               \
            __builtin_amdgcn_s_setprio(1);                                                  \
            _Pragma("unroll") for (int mi = 0; mi < 8; ++mi) {                              \
                const int row = mi * 16 + r16;                                              \
                const int o16 = row * 8 + ((kk * 4 + kb) ^ (row & 7));                      \
                bf16x8 af = *(const bf16x8*)((const char*)&lds[d][0][wm][0] + o16 * 16);    \
                _Pragma("unroll") for (int ni = 0; ni < 4; ++ni)                            \
                    acc[mi][ni] = __builtin_amdgcn_mfma_f32_16x16x32_bf16(af, bfr[ni], acc[mi][ni], 0, 0, 0); \
            }                                                                               \
            __builtin_amdgcn_s_setprio(0);                                                  \
        }                                                                                   \
    };                                                                                      \
    const int NT = (Kdim_) / 64;                                                            \
    stage(0);                                                                               \
    __syncthreads();                                                                        \
    for (int t = 0; t < NT; ++t) {                                                          \
        if (t + 1 < NT) stage(t + 1);                                                       \
        compute(t);                                                                         \
        __syncthreads();                                                                    \
    }                                                                                       \
    const int rquad = (lane >> 4) * 4;                                                      \
    const int cl    = lane & 15;

// ------ fused: V-projection (blocks 0..95) + cvt of q,k (blocks 96..255) ----
__global__ __launch_bounds__(512, 2)
void vprojcvt(const ushort_t* __restrict__ wv_, const ushort_t* __restrict__ vb_,
              const float* __restrict__ bv_, ushort_t* __restrict__ dvT_,
              const float* __restrict__ qf_, const float* __restrict__ kf_,
              ushort_t* __restrict__ qb_, ushort_t* __restrict__ kb_)
{
    if (blockIdx.x < 96) {
        const int id = blockIdx.x;
        const long long tM = (long long)(id % 3) * 256;    // feature rows (768)
        const long long tN = (long long)(id / 3) * 256;    // token cols (8192)
        const ushort_t* Ab = wv_;
        const ushort_t* Bb = vb_;

        GEMM256_CORE(Ab, 768, Bb, 768, 768)

#pragma unroll
        for (int mi = 0; mi < 8; ++mi) {
            const long long r = tM + wm * 128 + mi * 16 + rquad;
#pragma unroll
            for (int ni = 0; ni < 4; ++ni) {
                f32x4 v = acc[mi][ni];
                const long long c = tN + wn * 64 + ni * 16 + cl;
#pragma unroll
                for (int j = 0; j < 4; ++j)
                    dvT_[(r + j) * 8192 + c] = f2bf(v[j] + bv_[r + j]);
            }
        }
    } else {
        const long long stride = 160LL * 512;
        for (long long i = (long long)(blockIdx.x - 96) * 512 + threadIdx.x;
             i < 2LL * 1572864; i += stride) {
            const float* src; ushort_t* dst; long long off;
            if (i < 1572864) { src = qf_; dst = qb_; off = i; }
            else             { src = kf_; dst = kb_; off = i - 1572864; }
            f32x4v v4 = ((const f32x4v*)src)[off];
            u16x4 o = { f2bf(v4.x), f2bf(v4.y), f2bf(v4.z), f2bf(v4.w) };
            ((u16x4*)dst)[off] = o;
        }
    }
}

// ---------------- Q,K projections: grid (3,32,2) = 192 blocks, 1 round ------
__global__ __launch_bounds__(512, 2)
void projqk2(const ushort_t* __restrict__ qin, const ushort_t* __restrict__ kin,
             const ushort_t* __restrict__ Wqb, const ushort_t* __restrict__ Wkb,
             const float* __restrict__ bqv, const float* __restrict__ bkv,
             ushort_t* __restrict__ dq, ushort_t* __restrict__ dk)
{
    int bx, by, bz;
    xcd_remap(bx, by, bz);
    const int z = bz;
    const long long tM = (long long)by * 256;
    const long long tN = (long long)bx * 256;
    const ushort_t* Ab = z ? kin : qin;
    const ushort_t* Bb = z ? Wkb : Wqb;
    const float* bias  = z ? bkv : bqv;
    ushort_t* dst      = z ? dk : dq;

    GEMM256_CORE(Ab, 768, Bb, 768, 768)

#pragma unroll
    for (int mi = 0; mi < 8; ++mi) {
        const long long r = tM + wm * 128 + mi * 16 + rquad;
#pragma unroll
        for (int ni = 0; ni < 4; ++ni) {
            f32x4 v = acc[mi][ni];
            const long long c = tN + wn * 64 + ni * 16 + cl;
            const float bc = bias[c];
#pragma unroll
            for (int j = 0; j < 4; ++j)
                dst[(r + j) * 768 + c] = f2bf(v[j] + bc);
        }
    }
}

// ---- sexp: P~ = exp(scale*qp@kp^T) bf16. (8,8,4) = 256 blocks. No rowsum. ----
__global__ __launch_bounds__(512, 2)
void sexp2(const ushort_t* __restrict__ qp, const ushort_t* __restrict__ kp,
           ushort_t* __restrict__ P, float scale)
{
    int bx, by, bz;
    xcd_remap(bx, by, bz);
    const long long tM = (long long)by * 256;
    const long long tN = (long long)bx * 256;
    const int z = bz;
    const ushort_t* Ab = qp + (long long)z * 1572864;
    const ushort_t* Bb = kp + (long long)z * 1572864;

    GEMM256_CORE(Ab, 768, Bb, 768, 768)

    ushort_t* out = P + (long long)z * 4194304;
#pragma unroll
    for (int mi = 0; mi < 8; ++mi) {
        const long long r = tM + wm * 128 + mi * 16 + rquad;
#pragma unroll
        for (int ni = 0; ni < 4; ++ni) {
            f32x4 v = acc[mi][ni];
            const long long c = tN + wn * 64 + ni * 16 + cl;
#pragma unroll
            for (int j = 0; j < 4; ++j)
                out[(r + j) * 2048 + c] = f2bf(__expf(v[j] * scale));
        }
    }
}

// ============================================================================
// PVN: O = (P @ Vp^T) / rowsum. 128x128 / BK=64 core (32 K-steps — half the
// barrier/drain count of BK=32; 64KB LDS -> 2 blocks/CU, enough for the
// 384-block grid in one round). rowsum via ones-MFMA (C-layout aligned).
// 8-slot swizzle slot^(row&7) applied inverse-on-source + on-read (rule #21).
// ============================================================================
__global__ __launch_bounds__(256, 2)
void pvn_rs(const ushort_t* __restrict__ Pg, const ushort_t* __restrict__ vpT,
            ushort_t* __restrict__ Og)
{
    int bx, by, bz;
    xcd_remap(bx, by, bz);
    const long long tM = (long long)by * 128;
    const long long tN = (long long)bx * 128;
    const int z = bz;
    const ushort_t* Ab = Pg + (long long)z * 4194304;   // P: [2048][2048] bf16
    const ushort_t* Bb = vpT + (long long)z * 2048;     // vpT: [768][8192], batch = col offset

    __shared__ __align__(16) ushort_t lds[2][2][128 * 64];   // 64 KB
    const int tid  = threadIdx.x;
    const int lane = tid & 63;
    const int wave = tid >> 6;
    const int wr = wave >> 1, wc = wave & 1;

    const u16x8 oneb = {0x3F80,0x3F80,0x3F80,0x3F80,0x3F80,0x3F80,0x3F80,0x3F80};
    const bf16x8 ones = __builtin_bit_cast(bf16x8, oneb);

    f32x4 acc[4][4];
    f32x4 rs4[4];
#pragma unroll
    for (int i = 0; i < 4; ++i) {
        rs4[i] = (f32x4){0.f, 0.f, 0.f, 0.f};
#pragma unroll
        for (int j = 0; j < 4; ++j)
            acc[i][j] = (f32x4){0.f, 0.f, 0.f, 0.f};
    }

    auto stage = [&](int buf, int kt) {
        const int k0 = kt * 64;
#pragma unroll
        for (int rnd = 0; rnd < 4; ++rnd) {
            const int idx  = rnd * 256 + tid;        // 0..1023
            const int row  = idx >> 3;               // 128 rows, 8 slots/row
            const int slot = idx & 7;
            const int ssrc = slot ^ (row & 7);
            const ushort_t* ga = Ab + (tM + row) * 2048LL + k0 + ssrc * 8;
            const ushort_t* gb = Bb + (tN + row) * 8192LL + k0 + ssrc * 8;
            __builtin_amdgcn_global_load_lds((const __attribute__((address_space(1))) void*)ga,
                                             (__attribute__((address_space(3))) void*)&lds[buf][0][idx * 8], 16, 0, 0);
            __builtin_amdgcn_global_load_lds((const __attribute__((address_space(1))) void*)gb,
                                             (__attribute__((address_space(3))) void*)&lds[buf][1][idx * 8], 16, 0, 0);
        }
    };
    auto compute = [&](int buf) {
        const int kbb = lane >> 4;
        const int r16 = lane & 15;
#pragma unroll
        for (int kk = 0; kk < 2; ++kk) {
            bf16x8 af[4], bfr[4];
#pragma unroll
            for (int mi = 0; mi < 4; ++mi) {
                const int row = wr * 64 + mi * 16 + r16;
                const int o16 = row * 8 + ((kk * 4 + kbb) ^ (row & 7));
                af[mi] = *(const bf16x8*)((const char*)lds[buf][0] + o16 * 16);
            }
#pragma unroll
            for (int ni = 0; ni < 4; ++ni) {
                const int row = wc * 64 + ni * 16 + r16;
                const int o16 = row * 8 + ((kk * 4 + kbb) ^ (row & 7));
                bfr[ni] = *(const bf16x8*)((const char*)lds[buf][1] + o16 * 16);
            }
            __builtin_amdgcn_s_setprio(1);
#pragma unroll
            for (int mi = 0; mi < 4; ++mi) {
#pragma unroll
                for (int ni = 0; ni < 4; ++ni)
                    acc[mi][ni] = __builtin_amdgcn_mfma_f32_16x16x32_bf16(af[mi], bfr[ni], acc[mi][ni], 0, 0, 0);
                rs4[mi] = __builtin_amdgcn_mfma_f32_16x16x32_bf16(af[mi], ones, rs4[mi], 0, 0, 0);
            }
            __builtin_amdgcn_s_setprio(0);
        }
    };

    stage(0, 0);
    __syncthreads();
    int cur = 0;
    for (int kt = 0; kt + 1 < 32; ++kt) {
        stage(cur ^ 1, kt + 1);
        compute(cur);
        __syncthreads();
        cur ^= 1;
    }
    compute(cur);

    const int rquad = (lane >> 4) * 4;
    const int cl    = lane & 15;
    ushort_t* out = Og + (long long)z * 1572864;
#pragma unroll
    for (int mi = 0; mi < 4; ++mi) {
        const long long r = tM + wr * 64 + mi * 16 + rquad;
        float inv[4];
#pragma unroll
        for (int j = 0; j < 4; ++j)
            inv[j] = 1.0f / rs4[mi][j];
#pragma unroll
        for (int ni = 0; ni < 4; ++ni) {
            f32x4 v = acc[mi][ni];
            const long long c = tN + wc * 64 + ni * 16 + cl;
#pragma unroll
            for (int j = 0; j < 4; ++j)
                out[(r + j) * 768 + c] = f2bf(v[j] * inv[j]);
        }
    }
}

// ---------------- OUT: fp32 = O @ Wp^T + bp, 128x128 / BK=64 core -----------
__global__ __launch_bounds__(256, 2)
void gemm_out(const ushort_t* __restrict__ A, const ushort_t* __restrict__ B,
              float* __restrict__ Cg, const float* __restrict__ bias)
{
    int bx, by, bz;
    xcd_remap(bx, by, bz);
    const long long tM = (long long)by * 128;
    const long long tN = (long long)bx * 128;
    const ushort_t* Ab = A;
    const ushort_t* Bb = B;

    __shared__ __align__(16) ushort_t lds[2][2][128 * 64];   // 64 KB
    const int tid  = threadIdx.x;
    const int lane = tid & 63;
    const int wave = tid >> 6;
    const int wr = wave >> 1, wc = wave & 1;
    f32x4 acc[4][4];
#pragma unroll
    for (int i = 0; i < 4; ++i)
#pragma unroll
        for (int j = 0; j < 4; ++j)
            acc[i][j] = (f32x4){0.f, 0.f, 0.f, 0.f};

    auto stage = [&](int buf, int kt) {
        const int k0 = kt * 64;
#pragma unroll
        for (int rnd = 0; rnd < 4; ++rnd) {
            const int idx  = rnd * 256 + tid;
            const int row  = idx >> 3;
            const int slot = idx & 7;
            const int ssrc = slot ^ (row & 7);
            const ushort_t* ga = Ab + (tM + row) * 768LL + k0 + ssrc * 8;
            const ushort_t* gb = Bb + (tN + row) * 768LL + k0 + ssrc * 8;
            __builtin_amdgcn_global_load_lds((const __attribute__((address_space(1))) void*)ga,
                                             (__attribute__((address_space(3))) void*)&lds[buf][0][idx * 8], 16, 0, 0);
            __builtin_amdgcn_global_load_lds((const __attribute__((address_space(1))) void*)gb,
                                             (__attribute__((address_space(3))) void*)&lds[buf][1][idx * 8], 16, 0, 0);
        }
    };
    auto compute = [&](int buf) {
        const int kbb = lane >> 4;
        const int r16 = lane & 15;
#pragma unroll
        for (int kk = 0; kk < 2; ++kk) {
            bf16x8 af[4], bfr[4];
#pragma unroll
            for (int mi = 0; mi < 4; ++mi) {
                const int row = wr * 64 + mi * 16 + r16;
                const int o16 = row * 8 + ((kk * 4 + kbb) ^ (row & 7));
                af[mi] = *(const bf16x8*)((const char*)lds[buf][0] + o16 * 16);
            }
#pragma unroll
            for (int ni = 0; ni < 4; ++ni) {
                const int row = wc * 64 + ni * 16 + r16;
                const int o16 = row * 8 + ((kk * 4 + kbb) ^ (row & 7));
                bfr[ni] = *(const bf16x8*)((const char*)lds[buf][1] + o16 * 16);
            }
            __builtin_amdgcn_s_setprio(1);
#pragma unroll
            for (int mi = 0; mi < 4; ++mi)
#pragma unroll
                for (int ni = 0; ni < 4; ++ni)
                    acc[mi][ni] = __builtin_amdgcn_mfma_f32_16x16x32_bf16(af[mi], bfr[ni], acc[mi][ni], 0, 0, 0);
            __builtin_amdgcn_s_setprio(0);
        }
    };

    stage(0, 0);
    __syncthreads();
    int cur = 0;
    for (int kt = 0; kt + 1 < 12; ++kt) {
        stage(cur ^ 1, kt + 1);
        compute(cur);
        __syncthreads();
        cur ^= 1;
    }
    compute(cur);

    const int rquad = (lane >> 4) * 4;
    const int cl    = lane & 15;
#pragma unroll
    for (int mi = 0; mi < 4; ++mi) {
        const long long r = tM + wr * 64 + mi * 16 + rquad;
#pragma unroll
        for (int ni = 0; ni < 4; ++ni) {
            f32x4 v = acc[mi][ni];
            const long long c = tN + wc * 64 + ni * 16 + cl;
            const float bc = bias[c];
#pragma unroll
            for (int j = 0; j < 4; ++j)
                Cg[(r + j) * 768 + c] = v[j] + bc;
        }
    }
}

// ---------------- launch ----------------
extern "C" void kernel_launch(void* const* d_in, const int* in_sizes, int n_in,
                              void* d_out, int out_size, void* d_ws, size_t ws_size,
                              hipStream_t stream) {
    (void)in_sizes; (void)n_in; (void)out_size; (void)ws_size;
    const float* q  = (const float*)d_in[0];
    const float* k  = (const float*)d_in[1];
    const float* v  = (const float*)d_in[2];
    const float* Wq = (const float*)d_in[3];
    const float* bq = (const float*)d_in[4];
    const float* Wk = (const float*)d_in[5];
    const float* bk = (const float*)d_in[6];
    const float* Wv = (const float*)d_in[7];
    const float* bv = (const float*)d_in[8];
    const float* Wp = (const float*)d_in[9];
    const float* bp = (const float*)d_in[10];
    float* out = (float*)d_out;

    // ---- workspace layout (round-9 proven, no live-overlay) ----
    char* ws = (char*)d_ws;
    ushort_t* vb  = (ushort_t*)(ws);                 // [0, 12.6M)
    ushort_t* qb  = (ushort_t*)(ws + 12582912LL);
    ushort_t* kb  = (ushort_t*)(ws + 25165824LL);
    ushort_t* P   = (ushort_t*)(ws + 12582912LL);    // overlays dead qb,kb + gap
    ushort_t* Wqb = (ushort_t*)(ws + 46137344LL);
    ushort_t* Wkb = (ushort_t*)(ws + 47316992LL);
    ushort_t* Wvb = (ushort_t*)(ws + 48496640LL);
    ushort_t* Wpb = (ushort_t*)(ws + 49676288LL);
    ushort_t* qp  = (ushort_t*)(ws + 50855936LL);    // [8192][768] bf16
    ushort_t* kp  = (ushort_t*)(ws + 63438848LL);    // [8192][768] bf16
    ushort_t* vpT = (ushort_t*)(ws + 76021760LL);    // [768][8192] bf16
    ushort_t* Ob  = qp;                              // O overlays dead qp

    const float scale = 1.0f / sqrtf(768.0f);

    // 1) merged prep: cvt v + 4 weights
    cvt_all<<<8448, 256, 0, stream>>>(v, Wq, Wk, Wv, Wp, vb, Wqb, Wkb, Wvb, Wpb);

    // 2) fused: V-projection (96 tiles) + cvt of q,k (160 blocks)
    vprojcvt<<<256, 512, 0, stream>>>(Wvb, vb, bv, vpT, q, k, qb, kb);

    // 3) Q,K projections (192 tiles, 1 round)
    projqk2<<<dim3(3, 32, 2), 512, 0, stream>>>(qb, kb, Wqb, Wkb, bq, bk, qp, kp);

    // 4) P~ = exp(scale * QK^T)  (256 tiles, 1 round; no rowsum side-work)
    sexp2<<<dim3(8, 8, 4), 512, 0, stream>>>(qp, kp, P, scale);

    // 5) O = (P~ @ Vp^T) / rowsum   (rowsum via ones-MFMA; BK=64, 32 K-steps)
    pvn_rs<<<dim3(6, 16, 4), 256, 0, stream>>>(P, vpT, Ob);

    // 6) out = O @ Wp^T + bp  (BK=64, 12 K-steps)
    gemm_out<<<dim3(6, 64, 1), 256, 0, stream>>>(Ob, Wpb, out, bp);
}

// Round 14
// 147.497 us; speedup vs baseline: 1.3440x; 1.0012x over previous
//
#include <hip/hip_runtime.h>
#include <hip/hip_bf16.h>
#include <math.h>

typedef __bf16 bf16x8 __attribute__((ext_vector_type(8)));
typedef float  f32x4  __attribute__((ext_vector_type(4)));
typedef float  f32x4v __attribute__((ext_vector_type(4)));
typedef unsigned short ushort_t;
typedef ushort_t u16x4 __attribute__((ext_vector_type(4)));
typedef ushort_t u16x8 __attribute__((ext_vector_type(8)));

__device__ __forceinline__ ushort_t f2bf(float f) {
    unsigned u = __builtin_bit_cast(unsigned, f);
    u += 0x7FFFu + ((u >> 16) & 1u);
    return (ushort_t)(u >> 16);
}

// XCD-aware bijective remap (m157/m204). Requires total grid % 8 == 0.
__device__ __forceinline__ void xcd_remap(int& bx, int& by, int& bz) {
    const int gx = gridDim.x, gy = gridDim.y;
    const int nwg = gx * gy * gridDim.z;
    const int lin = (blockIdx.z * gy + blockIdx.y) * gx + blockIdx.x;
    const int chunk = nwg >> 3;
    int nid = (lin & 7) * chunk + (lin >> 3);
    bx = nid % gx; nid /= gx;
    by = nid % gy; bz = nid / gy;
}

// ---- merged prep launch: cvt v (6144 blocks) + 4 weights (4x576) ----
__global__ __launch_bounds__(256)
void cvt_all(const float* __restrict__ v, const float* __restrict__ Wq,
             const float* __restrict__ Wk, const float* __restrict__ Wv,
             const float* __restrict__ Wp,
             ushort_t* __restrict__ vb, ushort_t* __restrict__ Wqb,
             ushort_t* __restrict__ Wkb, ushort_t* __restrict__ Wvb,
             ushort_t* __restrict__ Wpb)
{
    const int b = blockIdx.x;
    if (b < 6144) {
        int i = b * 256 + threadIdx.x;
        f32x4v x = ((const f32x4v*)v)[i];
        u16x4 o = { f2bf(x.x), f2bf(x.y), f2bf(x.z), f2bf(x.w) };
        ((u16x4*)vb)[i] = o;
    } else {
        const int w = (b - 6144) / 576;
        const int bb = (b - 6144) % 576;
        const float* in  = w == 0 ? Wq : w == 1 ? Wk : w == 2 ? Wv : Wp;
        ushort_t*    out = w == 0 ? Wqb : w == 1 ? Wkb : w == 2 ? Wvb : Wpb;
        int i = bb * 256 + threadIdx.x;
        f32x4v x = ((const f32x4v*)in)[i];
        u16x4 o = { f2bf(x.x), f2bf(x.y), f2bf(x.z), f2bf(x.w) };
        ((u16x4*)out)[i] = o;
    }
}

// ============================================================================
// 256x256 / BK=64 / 8-wave 2-PHASE core (round-6 proven). T2 swizzle applied
// inverse-on-source (linear gload_lds dest, rule #21), T5 setprio.
// ============================================================================
#define GEMM256_CORE(Ab_, lda_, Bb_, ldb_, Kdim_)                                           \
    __shared__ __align__(16) ushort_t lds[2][2][2][128 * 64];                               \
    const int tid  = threadIdx.x;                                                           \
    const int lane = tid & 63;                                                              \
    const int wave = tid >> 6;                                                              \
    const int wm = wave >> 2, wn = wave & 3;                                                \
    const int r16 = lane & 15, kb = lane >> 4;                                              \
    f32x4 acc[8][4];                                                                        \
    _Pragma("unroll") for (int i = 0; i < 8; ++i)                                           \
        _Pragma("unroll") for (int j = 0; j < 4; ++j)                                       \
            acc[i][j] = (f32x4){0.f, 0.f, 0.f, 0.f};                                        \
    auto stage = [&](int kt) {                                                              \
        const int d  = kt & 1;                                                              \
        const int k0 = kt * 64;                                                             \
        _Pragma("unroll") for (int arr = 0; arr < 2; ++arr)                                 \
        _Pragma("unroll") for (int h = 0; h < 2; ++h)                                       \
        _Pragma("unroll") for (int l = 0; l < 2; ++l) {                                     \
            const int idx = l * 512 + tid;                                                  \
            const int row = idx >> 3, sl = idx & 7;                                         \
            const int ssrc = sl ^ (row & 7);                                                \
            const long long grow = h * 128 + row;                                           \
            const ushort_t* g = (arr == 0)                                                  \
                ? (Ab_) + (tM + grow) * (long long)(lda_) + k0 + ssrc * 8                   \
                : (Bb_) + (tN + grow) * (long long)(ldb_) + k0 + ssrc * 8;                  \
            ushort_t* lp = &lds[d][arr][h][idx * 8];                                        \
            __builtin_amdgcn_global_load_lds((const __attribute__((address_space(1))) void*)g, \
                                             (__attribute__((address_space(3))) void*)lp, 16, 0, 0); \
        }                                                                                   \
    };                                                                                      \
    auto compute = [&](int kt) {                                                            \
        const int d = kt & 1;                                                               \
        _Pragma("unroll") for (int kk = 0; kk < 2; ++kk) {                                  \
            bf16x8 bfr[4];                                                                  \
            _Pragma("unroll") for (int ni = 0; ni < 4; ++ni) {                              \
                const int row = (wn & 1) * 64 + ni * 16 + r16;                              \
                const int o16 = row * 8 + ((kk * 4 + kb) ^ (row & 7));                      \
                bfr[ni] = *(const bf16x8*)((const char*)&lds[d][1][wn >> 1][0] + o16 * 16); \
            }                                                                               \
            __builtin_amdgcn_s_setprio(1);                                                  \
            _Pragma("unroll") for (int mi = 0; mi < 8; ++mi) {                              \
                const int row = mi * 16 + r16;                                              \
                const int o16 = row * 8 + ((kk * 4 + kb) ^ (row & 7));                      \
                bf16x8 af = *(const bf16x8*)((const char*)&lds[d][0][wm][0] + o16 * 16);    \
                _Pragma("unroll") for (int ni = 0; ni < 4; ++ni)                            \
                    acc[mi][ni] = __builtin_amdgcn_mfma_f32_16x16x32_bf16(af, bfr[ni], acc[mi][ni], 0, 0, 0); \
            }                                                                               \
            __builtin_amdgcn_s_setprio(0);                                                  \
        }                                                                                   \
    };                                                                                      \
    const int NT = (Kdim_) / 64;                                                            \
    stage(0);                                                                               \
    __syncthreads();                                                                        \
    for (int t = 0; t < NT; ++t) {                                                          \
        if (t + 1 < NT) stage(t + 1);                                                       \
        compute(t);                                                                         \
        __syncthreads();                                                                    \
    }                                                                                       \
    const int rquad = (lane >> 4) * 4;                                                      \
    const int cl    = lane & 15;

// ------ fused: V-projection (blocks 0..95) + cvt of q,k (blocks 96..255) ----
__global__ __launch_bounds__(512, 2)
void vprojcvt(const ushort_t* __restrict__ wv_, const ushort_t* __restrict__ vb_,
              const float* __restrict__ bv_, ushort_t* __restrict__ dvT_,
              const float* __restrict__ qf_, const float* __restrict__ kf_,
              ushort_t* __restrict__ qb_, ushort_t* __restrict__ kb_)
{
    if (blockIdx.x < 96) {
        const int id = blockIdx.x;
        const long long tM = (long long)(id % 3) * 256;    // feature rows (768)
        const long long tN = (long long)(id / 3) * 256;    // token cols (8192)
        const ushort_t* Ab = wv_;
        const ushort_t* Bb = vb_;

        GEMM256_CORE(Ab, 768, Bb, 768, 768)

#pragma unroll
        for (int mi = 0; mi < 8; ++mi) {
            const long long r = tM + wm * 128 + mi * 16 + rquad;
#pragma unroll
            for (int ni = 0; ni < 4; ++ni) {
                f32x4 v = acc[mi][ni];
                const long long c = tN + wn * 64 + ni * 16 + cl;
#pragma unroll
                for (int j = 0; j < 4; ++j)
                    dvT_[(r + j) * 8192 + c] = f2bf(v[j] + bv_[r + j]);
            }
        }
    } else {
        const long long stride = 160LL * 512;
        for (long long i = (long long)(blockIdx.x - 96) * 512 + threadIdx.x;
             i < 2LL * 1572864; i += stride) {
            const float* src; ushort_t* dst; long long off;
            if (i < 1572864) { src = qf_; dst = qb_; off = i; }
            else             { src = kf_; dst = kb_; off = i - 1572864; }
            f32x4v v4 = ((const f32x4v*)src)[off];
            u16x4 o = { f2bf(v4.x), f2bf(v4.y), f2bf(v4.z), f2bf(v4.w) };
            ((u16x4*)dst)[off] = o;
        }
    }
}

// ---------------- Q,K projections: grid (3,32,2) = 192 blocks, 1 round ------
__global__ __launch_bounds__(512, 2)
void projqk2(const ushort_t* __restrict__ qin, const ushort_t* __restrict__ kin,
             const ushort_t* __restrict__ Wqb, const ushort_t* __restrict__ Wkb,
             const float* __restrict__ bqv, const float* __restrict__ bkv,
             ushort_t* __restrict__ dq, ushort_t* __restrict__ dk)
{
    int bx, by, bz;
    xcd_remap(bx, by, bz);
    const int z = bz;
    const long long tM = (long long)by * 256;
    const long long tN = (long long)bx * 256;
    const ushort_t* Ab = z ? kin : qin;
    const ushort_t* Bb = z ? Wkb : Wqb;
    const float* bias  = z ? bkv : bqv;
    ushort_t* dst      = z ? dk : dq;

    GEMM256_CORE(Ab, 768, Bb, 768, 768)

#pragma unroll
    for (int mi = 0; mi < 8; ++mi) {
        const long long r = tM + wm * 128 + mi * 16 + rquad;
#pragma unroll
        for (int ni = 0; ni < 4; ++ni) {
            f32x4 v = acc[mi][ni];
            const long long c = tN + wn * 64 + ni * 16 + cl;
            const float bc = bias[c];
#pragma unroll
            for (int j = 0; j < 4; ++j)
                dst[(r + j) * 768 + c] = f2bf(v[j] + bc);
        }
    }
}

// ============================================================================
// sexp: P~ = exp(scale * qp@kp^T) bf16. 128x128 / BK=64 / 256-thread core
// (pvn-proven structure: 64KB LDS -> 2 blocks/CU, co-resident blocks hide
// each other's barrier drains). Grid (16,16,4) = 1024 blocks.
// ============================================================================
__global__ __launch_bounds__(256, 2)
void sexp128(const ushort_t* __restrict__ qp, const ushort_t* __restrict__ kp,
             ushort_t* __restrict__ P, float scale)
{
    int bx, by, bz;
    xcd_remap(bx, by, bz);
    const long long tM = (long long)by * 128;
    const long long tN = (long long)bx * 128;
    const int z = bz;
    const ushort_t* Ab = qp + (long long)z * 1572864;
    const ushort_t* Bb = kp + (long long)z * 1572864;

    __shared__ __align__(16) ushort_t lds[2][2][128 * 64];   // 64 KB
    const int tid  = threadIdx.x;
    const int lane = tid & 63;
    const int wave = tid >> 6;
    const int wr = wave >> 1, wc = wave & 1;

    f32x4 acc[4][4];
#pragma unroll
    for (int i = 0; i < 4; ++i)
#pragma unroll
        for (int j = 0; j < 4; ++j)
            acc[i][j] = (f32x4){0.f, 0.f, 0.f, 0.f};

    auto stage = [&](int buf, int kt) {
        const int k0 = kt * 64;
#pragma unroll
        for (int rnd = 0; rnd < 4; ++rnd) {
            const int idx  = rnd * 256 + tid;        // 0..1023 (128 rows x 8 slots)
            const int row  = idx >> 3;
            const int slot = idx & 7;
            const int ssrc = slot ^ (row & 7);
            const ushort_t* ga = Ab + (tM + row) * 768LL + k0 + ssrc * 8;
            const ushort_t* gb = Bb + (tN + row) * 768LL + k0 + ssrc * 8;
            __builtin_amdgcn_global_load_lds((const __attribute__((address_space(1))) void*)ga,
                                             (__attribute__((address_space(3))) void*)&lds[buf][0][idx * 8], 16, 0, 0);
            __builtin_amdgcn_global_load_lds((const __attribute__((address_space(1))) void*)gb,
                                             (__attribute__((address_space(3))) void*)&lds[buf][1][idx * 8], 16, 0, 0);
        }
    };
    auto compute = [&](int buf) {
        const int kbb = lane >> 4;
        const int r16 = lane & 15;
#pragma unroll
        for (int kk = 0; kk < 2; ++kk) {
            bf16x8 af[4], bfr[4];
#pragma unroll
            for (int mi = 0; mi < 4; ++mi) {
                const int row = wr * 64 + mi * 16 + r16;
                const int o16 = row * 8 + ((kk * 4 + kbb) ^ (row & 7));
                af[mi] = *(const bf16x8*)((const char*)lds[buf][0] + o16 * 16);
            }
#pragma unroll
            for (int ni = 0; ni < 4; ++ni) {
                const int row = wc * 64 + ni * 16 + r16;
                const int o16 = row * 8 + ((kk * 4 + kbb) ^ (row & 7));
                bfr[ni] = *(const bf16x8*)((const char*)lds[buf][1] + o16 * 16);
            }
            __builtin_amdgcn_s_setprio(1);
#pragma unroll
            for (int mi = 0; mi < 4; ++mi)
#pragma unroll
                for (int ni = 0; ni < 4; ++ni)
                    acc[mi][ni] = __builtin_amdgcn_mfma_f32_16x16x32_bf16(af[mi], bfr[ni], acc[mi][ni], 0, 0, 0);
            __builtin_amdgcn_s_setprio(0);
        }
    };

    stage(0, 0);
    __syncthreads();
    int cur = 0;
    for (int kt = 0; kt + 1 < 12; ++kt) {
        stage(cur ^ 1, kt + 1);
        compute(cur);
        __syncthreads();
        cur ^= 1;
    }
    compute(cur);

    const int rquad = (lane >> 4) * 4;
    const int cl    = lane & 15;
    ushort_t* out = P + (long long)z * 4194304;
#pragma unroll
    for (int mi = 0; mi < 4; ++mi) {
        const long long r = tM + wr * 64 + mi * 16 + rquad;
#pragma unroll
        for (int ni = 0; ni < 4; ++ni) {
            f32x4 v = acc[mi][ni];
            const long long c = tN + wc * 64 + ni * 16 + cl;
#pragma unroll
            for (int j = 0; j < 4; ++j)
                out[(r + j) * 2048 + c] = f2bf(__expf(v[j] * scale));
        }
    }
}

// ============================================================================
// PVN: O = (P @ Vp^T) / rowsum. 128x128 / BK=64 core, rowsum via ones-MFMA.
// ============================================================================
__global__ __launch_bounds__(256, 2)
void pvn_rs(const ushort_t* __restrict__ Pg, const ushort_t* __restrict__ vpT,
            ushort_t* __restrict__ Og)
{
    int bx, by, bz;
    xcd_remap(bx, by, bz);
    const long long tM = (long long)by * 128;
    const long long tN = (long long)bx * 128;
    const int z = bz;
    const ushort_t* Ab = Pg + (long long)z * 4194304;   // P: [2048][2048] bf16
    const ushort_t* Bb = vpT + (long long)z * 2048;     // vpT: [768][8192], batch = col offset

    __shared__ __align__(16) ushort_t lds[2][2][128 * 64];   // 64 KB
    const int tid  = threadIdx.x;
    const int lane = tid & 63;
    const int wave = tid >> 6;
    const int wr = wave >> 1, wc = wave & 1;

    const u16x8 oneb = {0x3F80,0x3F80,0x3F80,0x3F80,0x3F80,0x3F80,0x3F80,0x3F80};
    const bf16x8 ones = __builtin_bit_cast(bf16x8, oneb);

    f32x4 acc[4][4];
    f32x4 rs4[4];
#pragma unroll
    for (int i = 0; i < 4; ++i) {
        rs4[i] = (f32x4){0.f, 0.f, 0.f, 0.f};
#pragma unroll
        for (int j = 0; j < 4; ++j)
            acc[i][j] = (f32x4){0.f, 0.f, 0.f, 0.f};
    }

    auto stage = [&](int buf, int kt) {
        const int k0 = kt * 64;
#pragma unroll
        for (int rnd = 0; rnd < 4; ++rnd) {
            const int idx  = rnd * 256 + tid;        // 0..1023
            const int row  = idx >> 3;               // 128 rows, 8 slots/row
            const int slot = idx & 7;
            const int ssrc = slot ^ (row & 7);
            const ushort_t* ga = Ab + (tM + row) * 2048LL + k0 + ssrc * 8;
            const ushort_t* gb = Bb + (tN + row) * 8192LL + k0 + ssrc * 8;
            __builtin_amdgcn_global_load_lds((const __attribute__((address_space(1))) void*)ga,
                                             (__attribute__((address_space(3))) void*)&lds[buf][0][idx * 8], 16, 0, 0);
            __builtin_amdgcn_global_load_lds((const __attribute__((address_space(1))) void*)gb,
                                             (__attribute__((address_space(3))) void*)&lds[buf][1][idx * 8], 16, 0, 0);
        }
    };
    auto compute = [&](int buf) {
        const int kbb = lane >> 4;
        const int r16 = lane & 15;
#pragma unroll
        for (int kk = 0; kk < 2; ++kk) {
            bf16x8 af[4], bfr[4];
#pragma unroll
            for (int mi = 0; mi < 4; ++mi) {
                const int row = wr * 64 + mi * 16 + r16;
                const int o16 = row * 8 + ((kk * 4 + kbb) ^ (row & 7));
                af[mi] = *(const bf16x8*)((const char*)lds[buf][0] + o16 * 16);
            }
#pragma unroll
            for (int ni = 0; ni < 4; ++ni) {
                const int row = wc * 64 + ni * 16 + r16;
                const int o16 = row * 8 + ((kk * 4 + kbb) ^ (row & 7));
                bfr[ni] = *(const bf16x8*)((const char*)lds[buf][1] + o16 * 16);
            }
            __builtin_amdgcn_s_setprio(1);
#pragma unroll
            for (int mi = 0; mi < 4; ++mi) {
#pragma unroll
                for (int ni = 0; ni < 4; ++ni)
                    acc[mi][ni] = __builtin_amdgcn_mfma_f32_16x16x32_bf16(af[mi], bfr[ni], acc[mi][ni], 0, 0, 0);
                rs4[mi] = __builtin_amdgcn_mfma_f32_16x16x32_bf16(af[mi], ones, rs4[mi], 0, 0, 0);
            }
            __builtin_amdgcn_s_setprio(0);
        }
    };

    stage(0, 0);
    __syncthreads();
    int cur = 0;
    for (int kt = 0; kt + 1 < 32; ++kt) {
        stage(cur ^ 1, kt + 1);
        compute(cur);
        __syncthreads();
        cur ^= 1;
    }
    compute(cur);

    const int rquad = (lane >> 4) * 4;
    const int cl    = lane & 15;
    ushort_t* out = Og + (long long)z * 1572864;
#pragma unroll
    for (int mi = 0; mi < 4; ++mi) {
        const long long r = tM + wr * 64 + mi * 16 + rquad;
        float inv[4];
#pragma unroll
        for (int j = 0; j < 4; ++j)
            inv[j] = 1.0f / rs4[mi][j];
#pragma unroll
        for (int ni = 0; ni < 4; ++ni) {
            f32x4 v = acc[mi][ni];
            const long long c = tN + wc * 64 + ni * 16 + cl;
#pragma unroll
            for (int j = 0; j < 4; ++j)
                out[(r + j) * 768 + c] = f2bf(v[j] * inv[j]);
        }
    }
}

// ---------------- OUT: fp32 = O @ Wp^T + bp, 128x128 / BK=64 core -----------
__global__ __launch_bounds__(256, 2)
void gemm_out(const ushort_t* __restrict__ A, const ushort_t* __restrict__ B,
              float* __restrict__ Cg, const float* __restrict__ bias)
{
    int bx, by, bz;
    xcd_remap(bx, by, bz);
    const long long tM = (long long)by * 128;
    const long long tN = (long long)bx * 128;
    const ushort_t* Ab = A;
    const ushort_t* Bb = B;

    __shared__ __align__(16) ushort_t lds[2][2][128 * 64];   // 64 KB
    const int tid  = threadIdx.x;
    const int lane = tid & 63;
    const int wave = tid >> 6;
    const int wr = wave >> 1, wc = wave & 1;
    f32x4 acc[4][4];
#pragma unroll
    for (int i = 0; i < 4; ++i)
#pragma unroll
        for (int j = 0; j < 4; ++j)
            acc[i][j] = (f32x4){0.f, 0.f, 0.f, 0.f};

    auto stage = [&](int buf, int kt) {
        const int k0 = kt * 64;
#pragma unroll
        for (int rnd = 0; rnd < 4; ++rnd) {
            const int idx  = rnd * 256 + tid;
            const int row  = idx >> 3;
            const int slot = idx & 7;
            const int ssrc = slot ^ (row & 7);
            const ushort_t* ga = Ab + (tM + row) * 768LL + k0 + ssrc * 8;
            const ushort_t* gb = Bb + (tN + row) * 768LL + k0 + ssrc * 8;
            __builtin_amdgcn_global_load_lds((const __attribute__((address_space(1))) void*)ga,
                                             (__attribute__((address_space(3))) void*)&lds[buf][0][idx * 8], 16, 0, 0);
            __builtin_amdgcn_global_load_lds((const __attribute__((address_space(1))) void*)gb,
                                             (__attribute__((address_space(3))) void*)&lds[buf][1][idx * 8], 16, 0, 0);
        }
    };
    auto compute = [&](int buf) {
        const int kbb = lane >> 4;
        const int r16 = lane & 15;
#pragma unroll
        for (int kk = 0; kk < 2; ++kk) {
            bf16x8 af[4], bfr[4];
#pragma unroll
            for (int mi = 0; mi < 4; ++mi) {
                const int row = wr * 64 + mi * 16 + r16;
                const int o16 = row * 8 + ((kk * 4 + kbb) ^ (row & 7));
                af[mi] = *(const bf16x8*)((const char*)lds[buf][0] + o16 * 16);
            }
#pragma unroll
            for (int ni = 0; ni < 4; ++ni) {
                const int row = wc * 64 + ni * 16 + r16;
                const int o16 = row * 8 + ((kk * 4 + kbb) ^ (row & 7));
                bfr[ni] = *(const bf16x8*)((const char*)lds[buf][1] + o16 * 16);
            }
            __builtin_amdgcn_s_setprio(1);
#pragma unroll
            for (int mi = 0; mi < 4; ++mi)
#pragma unroll
                for (int ni = 0; ni < 4; ++ni)
                    acc[mi][ni] = __builtin_amdgcn_mfma_f32_16x16x32_bf16(af[mi], bfr[ni], acc[mi][ni], 0, 0, 0);
            __builtin_amdgcn_s_setprio(0);
        }
    };

    stage(0, 0);
    __syncthreads();
    int cur = 0;
    for (int kt = 0; kt + 1 < 12; ++kt) {
        stage(cur ^ 1, kt + 1);
        compute(cur);
        __syncthreads();
        cur ^= 1;
    }
    compute(cur);

    const int rquad = (lane >> 4) * 4;
    const int cl    = lane & 15;
#pragma unroll
    for (int mi = 0; mi < 4; ++mi) {
        const long long r = tM + wr * 64 + mi * 16 + rquad;
#pragma unroll
        for (int ni = 0; ni < 4; ++ni) {
            f32x4 v = acc[mi][ni];
            const long long c = tN + wc * 64 + ni * 16 + cl;
            const float bc = bias[c];
#pragma unroll
            for (int j = 0; j < 4; ++j)
                Cg[(r + j) * 768 + c] = v[j] + bc;
        }
    }
}

// ---------------- launch ----------------
extern "C" void kernel_launch(void* const* d_in, const int* in_sizes, int n_in,
                              void* d_out, int out_size, void* d_ws, size_t ws_size,
                              hipStream_t stream) {
    (void)in_sizes; (void)n_in; (void)out_size; (void)ws_size;
    const float* q  = (const float*)d_in[0];
    const float* k  = (const float*)d_in[1];
    const float* v  = (const float*)d_in[2];
    const float* Wq = (const float*)d_in[3];
    const float* bq = (const float*)d_in[4];
    const float* Wk = (const float*)d_in[5];
    const float* bk = (const float*)d_in[6];
    const float* Wv = (const float*)d_in[7];
    const float* bv = (const float*)d_in[8];
    const float* Wp = (const float*)d_in[9];
    const float* bp = (const float*)d_in[10];
    float* out = (float*)d_out;

    // ---- workspace layout (round-9 proven, no live-overlay) ----
    char* ws = (char*)d_ws;
    ushort_t* vb  = (ushort_t*)(ws);                 // [0, 12.6M)
    ushort_t* qb  = (ushort_t*)(ws + 12582912LL);
    ushort_t* kb  = (ushort_t*)(ws + 25165824LL);
    ushort_t* P   = (ushort_t*)(ws + 12582912LL);    // overlays dead qb,kb + gap
    ushort_t* Wqb = (ushort_t*)(ws + 46137344LL);
    ushort_t* Wkb = (ushort_t*)(ws + 47316992LL);
    ushort_t* Wvb = (ushort_t*)(ws + 48496640LL);
    ushort_t* Wpb = (ushort_t*)(ws + 49676288LL);
    ushort_t* qp  = (ushort_t*)(ws + 50855936LL);    // [8192][768] bf16
    ushort_t* kp  = (ushort_t*)(ws + 63438848LL);    // [8192][768] bf16
    ushort_t* vpT = (ushort_t*)(ws + 76021760LL);    // [768][8192] bf16
    ushort_t* Ob  = qp;                              // O overlays dead qp

    const float scale = 1.0f / sqrtf(768.0f);

    // 1) merged prep: cvt v + 4 weights
    cvt_all<<<8448, 256, 0, stream>>>(v, Wq, Wk, Wv, Wp, vb, Wqb, Wkb, Wvb, Wpb);

    // 2) fused: V-projection (96 tiles) + cvt of q,k (160 blocks)
    vprojcvt<<<256, 512, 0, stream>>>(Wvb, vb, bv, vpT, q, k, qb, kb);

    // 3) Q,K projections (192 tiles, 1 round)
    projqk2<<<dim3(3, 32, 2), 512, 0, stream>>>(qb, kb, Wqb, Wkb, bq, bk, qp, kp);

    // 4) P~ = exp(scale * QK^T)  (128^2/BK=64 structure, 1024 blocks, 2/CU)
    sexp128<<<dim3(16, 16, 4), 256, 0, stream>>>(qp, kp, P, scale);

    // 5) O = (P~ @ Vp^T) / rowsum   (rowsum via ones-MFMA; BK=64, 32 K-steps)
    pvn_rs<<<dim3(6, 16, 4), 256, 0, stream>>>(P, vpT, Ob);

    // 6) out = O @ Wp^T + bp  (BK=64, 12 K-steps)
    gemm_out<<<dim3(6, 64, 1), 256, 0, stream>>>(Ob, Wpb, out, bp);
}